// Round 1
// baseline (1491.088 us; speedup 1.0000x reference)
//
#include <hip/hip_runtime.h>
#include <math.h>

#define B_  64
#define NS  512
#define NR  256
#define DD  1024
#define NEGV (-1e10f)

// ---------------------------------------------------------------- zero ws
__global__ __launch_bounds__(64) void zero_ws(double* ws) {
    if (threadIdx.x == 0) { ws[0] = 0.0; ws[1] = 0.0; }
}

// ---------------------------------------------------------------- att = masked span @ image^T
// block tile 64(s) x 64(r), BK=16, 256 threads, 4x4 micro-tile
__global__ __launch_bounds__(256) void att_kernel(
    const float* __restrict__ span, const float* __restrict__ image,
    const int* __restrict__ smask, const int* __restrict__ imask,
    float* __restrict__ att) {
    const int b  = blockIdx.z;
    const int s0 = blockIdx.y * 64;
    const int r0 = blockIdx.x * 64;
    __shared__ float As[16][68];   // [k][s]  (68 pad keeps float4 alignment: 272B rows)
    __shared__ float Bs[16][68];   // [k][r]
    const float* Ab = span  + (size_t)b * NS * DD;
    const float* Rb = image + (size_t)b * NR * DD;
    const int tid = threadIdx.x;
    const int tx = tid & 15, ty = tid >> 4;
    const int lrow = tid >> 2;        // 0..63
    const int lk   = (tid & 3) << 2;  // 0,4,8,12
    float acc[4][4] = {};
    for (int k0 = 0; k0 < DD; k0 += 16) {
        const float4 a = *reinterpret_cast<const float4*>(Ab + (size_t)(s0 + lrow) * DD + k0 + lk);
        const float4 c = *reinterpret_cast<const float4*>(Rb + (size_t)(r0 + lrow) * DD + k0 + lk);
        As[lk+0][lrow] = a.x; As[lk+1][lrow] = a.y; As[lk+2][lrow] = a.z; As[lk+3][lrow] = a.w;
        Bs[lk+0][lrow] = c.x; Bs[lk+1][lrow] = c.y; Bs[lk+2][lrow] = c.z; Bs[lk+3][lrow] = c.w;
        __syncthreads();
        #pragma unroll
        for (int k = 0; k < 16; ++k) {
            const float4 av = *reinterpret_cast<const float4*>(&As[k][ty * 4]);
            const float4 bv = *reinterpret_cast<const float4*>(&Bs[k][tx * 4]);
            const float avv[4] = {av.x, av.y, av.z, av.w};
            const float bvv[4] = {bv.x, bv.y, bv.z, bv.w};
            #pragma unroll
            for (int i = 0; i < 4; ++i)
                #pragma unroll
                for (int j = 0; j < 4; ++j)
                    acc[i][j] += avv[i] * bvv[j];
        }
        __syncthreads();
    }
    int sm[4], im[4];
    #pragma unroll
    for (int i = 0; i < 4; ++i) sm[i] = smask[b * NS + s0 + ty * 4 + i];
    #pragma unroll
    for (int j = 0; j < 4; ++j) im[j] = imask[b * NR + r0 + tx * 4 + j];
    #pragma unroll
    for (int i = 0; i < 4; ++i) {
        float4 o;
        float v;
        v = acc[i][0] * (float)(sm[i] * im[0]); o.x = (v != 0.0f) ? v : NEGV;
        v = acc[i][1] * (float)(sm[i] * im[1]); o.y = (v != 0.0f) ? v : NEGV;
        v = acc[i][2] * (float)(sm[i] * im[2]); o.z = (v != 0.0f) ? v : NEGV;
        v = acc[i][3] * (float)(sm[i] * im[3]); o.w = (v != 0.0f) ? v : NEGV;
        *reinterpret_cast<float4*>(att + ((size_t)b * NS + s0 + ty * 4 + i) * NR + r0 + tx * 4) = o;
    }
}

// ---------------------------------------------------------------- spans attend ROIs
// block = (32 s-rows, b). phase1: row softmax -> wT[256][36]. phase2: w @ image, + sum (span-af)^2
__global__ __launch_bounds__(256) void first_kernel(
    const float* __restrict__ span, const float* __restrict__ image,
    const int* __restrict__ smask, const int* __restrict__ imask,
    const float* __restrict__ att, float* __restrict__ att_first,
    double* __restrict__ ws) {
    const int b  = blockIdx.y;
    const int s0 = blockIdx.x * 32;
    __shared__ float wT[256][36];   // [r][s_rel]  (36*4=144B rows, float4-aligned)
    __shared__ float Is[32][132];   // [r_rel][d_rel]
    __shared__ float red[256];
    const int tid  = threadIdx.x;
    const int lane = tid & 63, wave = tid >> 6;

    // ---- phase 1: softmax rows (one row per wave iteration)
    for (int i = 0; i < 8; ++i) {
        const int srel = wave * 8 + i;
        const int s    = s0 + srel;
        const float4 v = *reinterpret_cast<const float4*>(att + ((size_t)b * NS + s) * NR + lane * 4);
        float m = fmaxf(fmaxf(v.x, v.y), fmaxf(v.z, v.w));
        #pragma unroll
        for (int off = 32; off; off >>= 1) m = fmaxf(m, __shfl_xor(m, off));
        float4 e;
        e.x = expf(v.x - m); e.y = expf(v.y - m); e.z = expf(v.z - m); e.w = expf(v.w - m);
        float sum = e.x + e.y + e.z + e.w;
        #pragma unroll
        for (int off = 32; off; off >>= 1) sum += __shfl_xor(sum, off);
        const float fac = (float)smask[b * NS + s] / sum;
        const int4 im4 = *reinterpret_cast<const int4*>(imask + b * NR + lane * 4);
        wT[lane * 4 + 0][srel] = e.x * fac * (float)im4.x;
        wT[lane * 4 + 1][srel] = e.y * fac * (float)im4.y;
        wT[lane * 4 + 2][srel] = e.z * fac * (float)im4.z;
        wT[lane * 4 + 3][srel] = e.w * fac * (float)im4.w;
    }
    __syncthreads();

    // ---- phase 2: att_first tile (32 x 1024) = w(32x256) @ image(256x1024)
    float sumsq = 0.0f;
    const int txd = tid & 31;   // d micro col group (x4)
    const int tys = tid >> 5;   // s micro row group (x4)
    const float* Ib = image + (size_t)b * NR * DD;
    for (int dc = 0; dc < 8; ++dc) {
        const int d0 = dc * 128;
        float acc[4][4] = {};
        for (int rc = 0; rc < 8; ++rc) {
            const int r0 = rc * 32;
            {   // stage image chunk 32 x 128
                const int rr = tid >> 3;
                const int cb = tid & 7;
                const float* src = Ib + (size_t)(r0 + rr) * DD + d0;
                #pragma unroll
                for (int q = 0; q < 4; ++q) {
                    *reinterpret_cast<float4*>(&Is[rr][(cb + 8 * q) * 4]) =
                        *reinterpret_cast<const float4*>(src + (cb + 8 * q) * 4);
                }
            }
            __syncthreads();
            #pragma unroll 4
            for (int rr = 0; rr < 32; ++rr) {
                const float4 wv = *reinterpret_cast<const float4*>(&wT[r0 + rr][tys * 4]);
                const float4 iv = *reinterpret_cast<const float4*>(&Is[rr][txd * 4]);
                const float wvv[4] = {wv.x, wv.y, wv.z, wv.w};
                const float ivv[4] = {iv.x, iv.y, iv.z, iv.w};
                #pragma unroll
                for (int i = 0; i < 4; ++i)
                    #pragma unroll
                    for (int j = 0; j < 4; ++j)
                        acc[i][j] += wvv[i] * ivv[j];
            }
            __syncthreads();
        }
        #pragma unroll
        for (int i = 0; i < 4; ++i) {
            const int s = s0 + tys * 4 + i;
            const size_t base = ((size_t)b * NS + s) * DD + d0 + txd * 4;
            const float4 af = {acc[i][0], acc[i][1], acc[i][2], acc[i][3]};
            *reinterpret_cast<float4*>(att_first + base) = af;
            const float4 sp = *reinterpret_cast<const float4*>(span + base);
            float dx;
            dx = sp.x - af.x; sumsq += dx * dx;
            dx = sp.y - af.y; sumsq += dx * dx;
            dx = sp.z - af.z; sumsq += dx * dx;
            dx = sp.w - af.w; sumsq += dx * dx;
        }
    }
    red[tid] = sumsq; __syncthreads();
    for (int off = 128; off; off >>= 1) {
        if (tid < off) red[tid] += red[tid + off];
        __syncthreads();
    }
    if (tid == 0) atomicAdd(ws, (double)red[0]);
}

// ---------------------------------------------------------------- ROIs attend spans
// block = (32 r-cols, b). phase1: column softmax stats. phase2: w2^T @ span, + sum (image-as)^2
__global__ __launch_bounds__(256) void second_kernel(
    const float* __restrict__ span, const float* __restrict__ image,
    const int* __restrict__ smask, const int* __restrict__ imask,
    const float* __restrict__ att, double* __restrict__ ws) {
    const int b  = blockIdx.y;
    const int r0 = blockIdx.x * 32;
    __shared__ float w2s[32][36];   // [s_rel][r_rel]
    __shared__ float Ss[32][132];   // [s_rel][d_rel]
    __shared__ float mArr[32], fArr[32];
    __shared__ float redm[8][32];
    __shared__ float red[256];
    const int tid = threadIdx.x;

    // ---- phase 1: per-column (over s) max and exp-sum
    const int rr = tid & 31, q = tid >> 5;
    const float* attb = att + (size_t)b * NS * NR + r0 + rr;
    float mloc = -3.4e38f;
    for (int t = 0; t < 64; ++t)
        mloc = fmaxf(mloc, attb[(size_t)(q * 64 + t) * NR]);
    redm[q][rr] = mloc;
    __syncthreads();
    if (tid < 32) {
        float m = redm[0][tid];
        #pragma unroll
        for (int qq = 1; qq < 8; ++qq) m = fmaxf(m, redm[qq][tid]);
        mArr[tid] = m;
    }
    __syncthreads();
    const float mcol = mArr[rr];
    float sloc = 0.0f;
    for (int t = 0; t < 64; ++t)
        sloc += expf(attb[(size_t)(q * 64 + t) * NR] - mcol);
    redm[q][rr] = sloc;
    __syncthreads();
    if (tid < 32) {
        float s = 0.0f;
        #pragma unroll
        for (int qq = 0; qq < 8; ++qq) s += redm[qq][tid];
        fArr[tid] = (float)imask[b * NR + r0 + tid] / s;
    }
    __syncthreads();

    // ---- phase 2: att_second tile (32 x 1024) = w2(32x512) @ span(512x1024)
    float sumsq = 0.0f;
    const int txd = tid & 31;   // d micro
    const int tyr = tid >> 5;   // r micro (x4)
    const float* Sb = span + (size_t)b * NS * DD;
    for (int dc = 0; dc < 8; ++dc) {
        const int d0 = dc * 128;
        float acc[4][4] = {};
        for (int sc = 0; sc < 16; ++sc) {
            const int sb0 = sc * 32;
            {   // stage span chunk 32 x 128
                const int sr = tid >> 3;
                const int cb = tid & 7;
                const float* src = Sb + (size_t)(sb0 + sr) * DD + d0;
                #pragma unroll
                for (int qq = 0; qq < 4; ++qq) {
                    *reinterpret_cast<float4*>(&Ss[sr][(cb + 8 * qq) * 4]) =
                        *reinterpret_cast<const float4*>(src + (cb + 8 * qq) * 4);
                }
            }
            {   // compute w2 chunk 32(s) x 32(r) on the fly
                const int ss = tid >> 3;
                const int rq = (tid & 7) * 4;
                const int s  = sb0 + ss;
                const float4 v = *reinterpret_cast<const float4*>(att + ((size_t)b * NS + s) * NR + r0 + rq);
                const float smv = (float)smask[b * NS + s];
                float4 w;
                w.x = expf(v.x - mArr[rq + 0]) * fArr[rq + 0] * smv;
                w.y = expf(v.y - mArr[rq + 1]) * fArr[rq + 1] * smv;
                w.z = expf(v.z - mArr[rq + 2]) * fArr[rq + 2] * smv;
                w.w = expf(v.w - mArr[rq + 3]) * fArr[rq + 3] * smv;
                *reinterpret_cast<float4*>(&w2s[ss][rq]) = w;
            }
            __syncthreads();
            #pragma unroll 4
            for (int ss = 0; ss < 32; ++ss) {
                const float4 wv = *reinterpret_cast<const float4*>(&w2s[ss][tyr * 4]);
                const float4 sv = *reinterpret_cast<const float4*>(&Ss[ss][txd * 4]);
                const float wvv[4] = {wv.x, wv.y, wv.z, wv.w};
                const float svv[4] = {sv.x, sv.y, sv.z, sv.w};
                #pragma unroll
                for (int i = 0; i < 4; ++i)
                    #pragma unroll
                    for (int j = 0; j < 4; ++j)
                        acc[i][j] += wvv[i] * svv[j];
            }
            __syncthreads();
        }
        #pragma unroll
        for (int i = 0; i < 4; ++i) {
            const int r = r0 + tyr * 4 + i;
            const float4 iv = *reinterpret_cast<const float4*>(image + ((size_t)b * NR + r) * DD + d0 + txd * 4);
            float dx;
            dx = iv.x - acc[i][0]; sumsq += dx * dx;
            dx = iv.y - acc[i][1]; sumsq += dx * dx;
            dx = iv.z - acc[i][2]; sumsq += dx * dx;
            dx = iv.w - acc[i][3]; sumsq += dx * dx;
        }
    }
    red[tid] = sumsq; __syncthreads();
    for (int off = 128; off; off >>= 1) {
        if (tid < off) red[tid] += red[tid + off];
        __syncthreads();
    }
    if (tid == 0) atomicAdd(ws + 1, (double)red[0]);
}

// ---------------------------------------------------------------- final score
__global__ __launch_bounds__(64) void score_kernel(const double* __restrict__ ws, float* __restrict__ out) {
    if (threadIdx.x == 0) {
        out[0] = (float)(ws[0] / (double)((size_t)B_ * NS * DD) +
                         ws[1] / (double)((size_t)B_ * NR * DD));
    }
}

extern "C" void kernel_launch(void* const* d_in, const int* in_sizes, int n_in,
                              void* d_out, int out_size, void* d_ws, size_t ws_size,
                              hipStream_t stream) {
    const float* span  = (const float*)d_in[0];
    const float* image = (const float*)d_in[1];
    const int*   smask = (const int*)d_in[2];
    const int*   imask = (const int*)d_in[3];
    float* out       = (float*)d_out;
    float* att_first = out + 1;
    float* att       = out + 1 + (size_t)B_ * NS * DD;
    double* ws = (double*)d_ws;

    hipLaunchKernelGGL(zero_ws, dim3(1), dim3(64), 0, stream, ws);
    hipLaunchKernelGGL(att_kernel, dim3(NR / 64, NS / 64, B_), dim3(256), 0, stream,
                       span, image, smask, imask, att);
    hipLaunchKernelGGL(first_kernel, dim3(NS / 32, B_), dim3(256), 0, stream,
                       span, image, smask, imask, att, att_first, ws);
    hipLaunchKernelGGL(second_kernel, dim3(NR / 32, B_), dim3(256), 0, stream,
                       span, image, smask, imask, att, ws);
    hipLaunchKernelGGL(score_kernel, dim3(1), dim3(64), 0, stream, ws, out);
}

// Round 2
// 462.322 us; speedup vs baseline: 3.2252x; 3.2252x over previous
//
#include <hip/hip_runtime.h>
#include <hip/hip_bf16.h>
#include <math.h>

#define B_  64
#define NS  512
#define NR  256
#define DD  1024
#define NEGV (-1e10f)

typedef __attribute__((ext_vector_type(4))) float f32x4;
typedef __attribute__((ext_vector_type(8))) short bf16x8;
typedef __attribute__((ext_vector_type(8))) unsigned short u16x8;

__device__ __forceinline__ unsigned short f2bf(float x) {
    unsigned u = __builtin_bit_cast(unsigned, x);
    unsigned r = u + 0x7FFFu + ((u >> 16) & 1u);
    return (unsigned short)(r >> 16);
}
__device__ __forceinline__ float bf2f(unsigned short h) {
    unsigned u = ((unsigned)h) << 16;
    return __builtin_bit_cast(float, u);
}

// ---------------------------------------------------------------- zero ws
__global__ __launch_bounds__(64) void zero_ws(double* ws) {
    if (threadIdx.x == 0) { ws[0] = 0.0; ws[1] = 0.0; }
}

// ================================================================ stage 1
// att = masked span @ image^T, bf16 hi/lo split MFMA (3 passes), 128x128 tile
__global__ __launch_bounds__(256) void att_mfma(
    const float* __restrict__ span, const float* __restrict__ image,
    const int* __restrict__ smask, const int* __restrict__ imask,
    float* __restrict__ att) {
    const int b  = blockIdx.z;
    const int s0 = blockIdx.y * 128;
    const int r0 = blockIdx.x * 128;
    __shared__ unsigned short Ah[128][40], Al[128][40], Bh[128][40], Bl[128][40];
    const int tid  = threadIdx.x;
    const int lane = tid & 63;
    const int w    = tid >> 6;
    const int wso  = (w >> 1) * 64;   // wave s offset in tile
    const int wro  = (w & 1) * 64;    // wave r offset in tile
    const float* Sp = span  + ((size_t)b * NS + s0) * DD;
    const float* Im = image + ((size_t)b * NR + r0) * DD;

    f32x4 acc[4][4];
    #pragma unroll
    for (int i = 0; i < 4; ++i)
        #pragma unroll
        for (int j = 0; j < 4; ++j) acc[i][j] = (f32x4){0.f, 0.f, 0.f, 0.f};

    const int krel = (tid & 7) * 4;   // 0..28
    const int row0 = tid >> 3;        // 0..31
    const int fr   = lane & 15;
    const int fk   = (lane >> 4) * 8;

    for (int k0 = 0; k0 < DD; k0 += 32) {
        #pragma unroll
        for (int p = 0; p < 4; ++p) {
            const int row = row0 + p * 32;
            const float4 a = *reinterpret_cast<const float4*>(Sp + (size_t)row * DD + k0 + krel);
            const float4 c = *reinterpret_cast<const float4*>(Im + (size_t)row * DD + k0 + krel);
            ushort4 hi, lo;
            hi.x = f2bf(a.x); lo.x = f2bf(a.x - bf2f(hi.x));
            hi.y = f2bf(a.y); lo.y = f2bf(a.y - bf2f(hi.y));
            hi.z = f2bf(a.z); lo.z = f2bf(a.z - bf2f(hi.z));
            hi.w = f2bf(a.w); lo.w = f2bf(a.w - bf2f(hi.w));
            *reinterpret_cast<ushort4*>(&Ah[row][krel]) = hi;
            *reinterpret_cast<ushort4*>(&Al[row][krel]) = lo;
            hi.x = f2bf(c.x); lo.x = f2bf(c.x - bf2f(hi.x));
            hi.y = f2bf(c.y); lo.y = f2bf(c.y - bf2f(hi.y));
            hi.z = f2bf(c.z); lo.z = f2bf(c.z - bf2f(hi.z));
            hi.w = f2bf(c.w); lo.w = f2bf(c.w - bf2f(hi.w));
            *reinterpret_cast<ushort4*>(&Bh[row][krel]) = hi;
            *reinterpret_cast<ushort4*>(&Bl[row][krel]) = lo;
        }
        __syncthreads();
        bf16x8 ah[4], al[4], bh[4], bl[4];
        #pragma unroll
        for (int mf = 0; mf < 4; ++mf) {
            ah[mf] = *reinterpret_cast<const bf16x8*>(&Ah[wso + mf * 16 + fr][fk]);
            al[mf] = *reinterpret_cast<const bf16x8*>(&Al[wso + mf * 16 + fr][fk]);
            bh[mf] = *reinterpret_cast<const bf16x8*>(&Bh[wro + mf * 16 + fr][fk]);
            bl[mf] = *reinterpret_cast<const bf16x8*>(&Bl[wro + mf * 16 + fr][fk]);
        }
        #pragma unroll
        for (int mf = 0; mf < 4; ++mf)
            #pragma unroll
            for (int nf = 0; nf < 4; ++nf) {
                acc[mf][nf] = __builtin_amdgcn_mfma_f32_16x16x32_bf16(ah[mf], bh[nf], acc[mf][nf], 0, 0, 0);
                acc[mf][nf] = __builtin_amdgcn_mfma_f32_16x16x32_bf16(ah[mf], bl[nf], acc[mf][nf], 0, 0, 0);
                acc[mf][nf] = __builtin_amdgcn_mfma_f32_16x16x32_bf16(al[mf], bh[nf], acc[mf][nf], 0, 0, 0);
            }
        __syncthreads();
    }
    // epilogue: mask + zero->NEG, C/D layout col=lane&15, row=(lane>>4)*4+i
    const int fq = lane >> 4;
    int imv[4];
    #pragma unroll
    for (int nf = 0; nf < 4; ++nf) imv[nf] = imask[b * NR + r0 + wro + nf * 16 + fr];
    #pragma unroll
    for (int mf = 0; mf < 4; ++mf) {
        #pragma unroll
        for (int i = 0; i < 4; ++i) {
            const int s = s0 + wso + mf * 16 + fq * 4 + i;
            const int sm = smask[b * NS + s];
            float* orow = att + ((size_t)b * NS + s) * NR + r0 + wro;
            #pragma unroll
            for (int nf = 0; nf < 4; ++nf) {
                const float v = acc[mf][nf][i] * (float)(sm * imv[nf]);
                orow[nf * 16 + fr] = (v != 0.0f) ? v : NEGV;
            }
        }
    }
}

// ================================================================ transpose f32 -> bf16 (dst[b][d][n] = src[b][n][d])
__global__ __launch_bounds__(256) void transpose_bf16(
    const float* __restrict__ src, unsigned short* __restrict__ dst, int N) {
    const int b = blockIdx.z, n0 = blockIdx.y * 32, d0 = blockIdx.x * 32;
    __shared__ unsigned short T[32][36];
    const int t = threadIdx.x;
    {
        const int n = t >> 3, dq = (t & 7) * 4;
        const float4 v = *reinterpret_cast<const float4*>(src + ((size_t)b * N + n0 + n) * DD + d0 + dq);
        T[dq + 0][n] = f2bf(v.x); T[dq + 1][n] = f2bf(v.y);
        T[dq + 2][n] = f2bf(v.z); T[dq + 3][n] = f2bf(v.w);
    }
    __syncthreads();
    {
        const int d = t >> 3, nq = (t & 7) * 4;
        *reinterpret_cast<ushort4*>(dst + ((size_t)b * DD + d0 + d) * N + n0 + nq) =
            *reinterpret_cast<const ushort4*>(&T[d][nq]);
    }
}

// ================================================================ softmax stats
__global__ __launch_bounds__(256) void stats_row(
    const float* __restrict__ att, const int* __restrict__ smask,
    float* __restrict__ m1, float* __restrict__ f1) {
    const int b = blockIdx.y;
    const int s = blockIdx.x * 4 + (threadIdx.x >> 6);
    const int lane = threadIdx.x & 63;
    const float* row = att + ((size_t)b * NS + s) * NR;
    const float4 v = *reinterpret_cast<const float4*>(row + lane * 4);
    float m = fmaxf(fmaxf(v.x, v.y), fmaxf(v.z, v.w));
    #pragma unroll
    for (int off = 32; off; off >>= 1) m = fmaxf(m, __shfl_xor(m, off));
    float e = expf(v.x - m) + expf(v.y - m) + expf(v.z - m) + expf(v.w - m);
    #pragma unroll
    for (int off = 32; off; off >>= 1) e += __shfl_xor(e, off);
    if (lane == 0) {
        m1[b * NS + s] = m;
        f1[b * NS + s] = (float)smask[b * NS + s] / e;
    }
}

__global__ __launch_bounds__(256) void stats_col(
    const float* __restrict__ att, const int* __restrict__ imask,
    float* __restrict__ m2, float* __restrict__ f2) {
    const int b = blockIdx.y, r0 = blockIdx.x * 64;
    const int tid = threadIdx.x, c = tid & 63, q = tid >> 6;
    __shared__ float red[4][64];
    __shared__ float mcol[64];
    const float* base = att + (size_t)b * NS * NR + r0 + c;
    float m = -3.4e38f;
    for (int s = q; s < NS; s += 4) m = fmaxf(m, base[(size_t)s * NR]);
    red[q][c] = m;
    __syncthreads();
    if (tid < 64) mcol[tid] = fmaxf(fmaxf(red[0][tid], red[1][tid]), fmaxf(red[2][tid], red[3][tid]));
    __syncthreads();
    const float mc = mcol[c];
    float ssum = 0.0f;
    for (int s = q; s < NS; s += 4) ssum += expf(base[(size_t)s * NR] - mc);
    red[q][c] = ssum;
    __syncthreads();
    if (tid < 64) {
        const float tot = red[0][tid] + red[1][tid] + red[2][tid] + red[3][tid];
        m2[b * NR + r0 + tid] = mcol[tid];
        f2[b * NR + r0 + tid] = (float)imask[b * NR + r0 + tid] / tot;
    }
}

// ================================================================ stage 2: att_first = w1 @ image, + MSE(span, att_first)
__global__ __launch_bounds__(256) void first_mfma(
    const float* __restrict__ span, const unsigned short* __restrict__ imgT,
    const int* __restrict__ imask, const float* __restrict__ att,
    const float* __restrict__ m1, const float* __restrict__ f1,
    float* __restrict__ att_first, double* __restrict__ wsum) {
    const int b = blockIdx.z, s0 = blockIdx.y * 64, d0 = blockIdx.x * 256;
    __shared__ unsigned short Wc[64][72];    // w1 chunk [s][r]
    __shared__ unsigned short Bc[256][72];   // imageT chunk [d][r]
    __shared__ float m1s[64], f1s[64];
    __shared__ float redsum[256];
    const int tid = threadIdx.x, lane = tid & 63, w = tid >> 6;
    if (tid < 64) { m1s[tid] = m1[b * NS + s0 + tid]; f1s[tid] = f1[b * NS + s0 + tid]; }
    f32x4 acc[4][4];
    #pragma unroll
    for (int i = 0; i < 4; ++i)
        #pragma unroll
        for (int j = 0; j < 4; ++j) acc[i][j] = (f32x4){0.f, 0.f, 0.f, 0.f};
    const int rrel = tid & 63, sgrp = tid >> 6;
    const int fr = lane & 15, fk0 = (lane >> 4) * 8;
    __syncthreads();
    for (int k0 = 0; k0 < NR; k0 += 64) {
        const float fim = (float)imask[b * NR + k0 + rrel];
        #pragma unroll
        for (int j = 0; j < 16; ++j) {
            const int srel = sgrp * 16 + j;
            const float a = att[((size_t)b * NS + s0 + srel) * NR + k0 + rrel];
            Wc[srel][rrel] = f2bf(expf(a - m1s[srel]) * f1s[srel] * fim);
        }
        const unsigned short* bsrc = imgT + ((size_t)b * DD + d0 + tid) * NR + k0;
        #pragma unroll
        for (int q = 0; q < 8; ++q)
            *reinterpret_cast<u16x8*>(&Bc[tid][q * 8]) = *reinterpret_cast<const u16x8*>(bsrc + q * 8);
        __syncthreads();
        #pragma unroll
        for (int ks = 0; ks < 2; ++ks) {
            bf16x8 aF[4], bF[4];
            #pragma unroll
            for (int mf = 0; mf < 4; ++mf) aF[mf] = *reinterpret_cast<const bf16x8*>(&Wc[mf * 16 + fr][ks * 32 + fk0]);
            #pragma unroll
            for (int nf = 0; nf < 4; ++nf) bF[nf] = *reinterpret_cast<const bf16x8*>(&Bc[w * 64 + nf * 16 + fr][ks * 32 + fk0]);
            #pragma unroll
            for (int mf = 0; mf < 4; ++mf)
                #pragma unroll
                for (int nf = 0; nf < 4; ++nf)
                    acc[mf][nf] = __builtin_amdgcn_mfma_f32_16x16x32_bf16(aF[mf], bF[nf], acc[mf][nf], 0, 0, 0);
        }
        __syncthreads();
    }
    float sumsq = 0.0f;
    const int fq = lane >> 4;
    #pragma unroll
    for (int mf = 0; mf < 4; ++mf) {
        #pragma unroll
        for (int i = 0; i < 4; ++i) {
            const int s = s0 + mf * 16 + fq * 4 + i;
            const size_t rowoff = ((size_t)b * NS + s) * DD + d0 + w * 64;
            #pragma unroll
            for (int nf = 0; nf < 4; ++nf) {
                const float v = acc[mf][nf][i];
                const float sp = span[rowoff + nf * 16 + fr];
                att_first[rowoff + nf * 16 + fr] = v;
                const float dx = sp - v;
                sumsq += dx * dx;
            }
        }
    }
    redsum[tid] = sumsq; __syncthreads();
    for (int off = 128; off; off >>= 1) {
        if (tid < off) redsum[tid] += redsum[tid + off];
        __syncthreads();
    }
    if (tid == 0) atomicAdd(wsum, (double)redsum[0]);
}

// ================================================================ stage 3: att_second = w2 @ span, + MSE(image, att_second)
__global__ __launch_bounds__(256) void second_mfma(
    const float* __restrict__ image, const unsigned short* __restrict__ spT,
    const int* __restrict__ smask, const float* __restrict__ att,
    const float* __restrict__ m2, const float* __restrict__ f2,
    double* __restrict__ wsum) {
    const int b = blockIdx.z, r0 = blockIdx.y * 64, d0 = blockIdx.x * 256;
    __shared__ unsigned short Wc[64][72];    // w2 chunk [r][s]
    __shared__ unsigned short Bc[256][72];   // spanT chunk [d][s]
    __shared__ float redsum[256];
    const int tid = threadIdx.x, lane = tid & 63, w = tid >> 6;
    const int rrel = tid & 63, sgrp = tid >> 6;
    const float m2r = m2[b * NR + r0 + rrel];
    const float f2r = f2[b * NR + r0 + rrel];
    f32x4 acc[4][4];
    #pragma unroll
    for (int i = 0; i < 4; ++i)
        #pragma unroll
        for (int j = 0; j < 4; ++j) acc[i][j] = (f32x4){0.f, 0.f, 0.f, 0.f};
    const int fr = lane & 15, fk0 = (lane >> 4) * 8;
    for (int k0 = 0; k0 < NS; k0 += 64) {
        #pragma unroll
        for (int j = 0; j < 16; ++j) {
            const int srel = sgrp * 16 + j;
            const float a = att[((size_t)b * NS + k0 + srel) * NR + r0 + rrel];
            const float smv = (float)smask[b * NS + k0 + srel];
            Wc[rrel][srel] = f2bf(expf(a - m2r) * f2r * smv);
        }
        const unsigned short* bsrc = spT + ((size_t)b * DD + d0 + tid) * NS + k0;
        #pragma unroll
        for (int q = 0; q < 8; ++q)
            *reinterpret_cast<u16x8*>(&Bc[tid][q * 8]) = *reinterpret_cast<const u16x8*>(bsrc + q * 8);
        __syncthreads();
        #pragma unroll
        for (int ks = 0; ks < 2; ++ks) {
            bf16x8 aF[4], bF[4];
            #pragma unroll
            for (int mf = 0; mf < 4; ++mf) aF[mf] = *reinterpret_cast<const bf16x8*>(&Wc[mf * 16 + fr][ks * 32 + fk0]);
            #pragma unroll
            for (int nf = 0; nf < 4; ++nf) bF[nf] = *reinterpret_cast<const bf16x8*>(&Bc[w * 64 + nf * 16 + fr][ks * 32 + fk0]);
            #pragma unroll
            for (int mf = 0; mf < 4; ++mf)
                #pragma unroll
                for (int nf = 0; nf < 4; ++nf)
                    acc[mf][nf] = __builtin_amdgcn_mfma_f32_16x16x32_bf16(aF[mf], bF[nf], acc[mf][nf], 0, 0, 0);
        }
        __syncthreads();
    }
    float sumsq = 0.0f;
    const int fq = lane >> 4;
    #pragma unroll
    for (int mf = 0; mf < 4; ++mf) {
        #pragma unroll
        for (int i = 0; i < 4; ++i) {
            const int r = r0 + mf * 16 + fq * 4 + i;
            const size_t rowoff = ((size_t)b * NR + r) * DD + d0 + w * 64;
            #pragma unroll
            for (int nf = 0; nf < 4; ++nf) {
                const float dx = image[rowoff + nf * 16 + fr] - acc[mf][nf][i];
                sumsq += dx * dx;
            }
        }
    }
    redsum[tid] = sumsq; __syncthreads();
    for (int off = 128; off; off >>= 1) {
        if (tid < off) redsum[tid] += redsum[tid + off];
        __syncthreads();
    }
    if (tid == 0) atomicAdd(wsum + 1, (double)redsum[0]);
}

// ================================================================ fallback f32 kernels (used when ws too small)
__global__ __launch_bounds__(256) void first_kernel(
    const float* __restrict__ span, const float* __restrict__ image,
    const int* __restrict__ smask, const int* __restrict__ imask,
    const float* __restrict__ att, float* __restrict__ att_first,
    double* __restrict__ ws) {
    const int b  = blockIdx.y;
    const int s0 = blockIdx.x * 32;
    __shared__ float wT[256][36];
    __shared__ float Is[32][132];
    __shared__ float red[256];
    const int tid  = threadIdx.x;
    const int lane = tid & 63, wave = tid >> 6;
    for (int i = 0; i < 8; ++i) {
        const int srel = wave * 8 + i;
        const int s    = s0 + srel;
        const float4 v = *reinterpret_cast<const float4*>(att + ((size_t)b * NS + s) * NR + lane * 4);
        float m = fmaxf(fmaxf(v.x, v.y), fmaxf(v.z, v.w));
        #pragma unroll
        for (int off = 32; off; off >>= 1) m = fmaxf(m, __shfl_xor(m, off));
        float4 e;
        e.x = expf(v.x - m); e.y = expf(v.y - m); e.z = expf(v.z - m); e.w = expf(v.w - m);
        float sum = e.x + e.y + e.z + e.w;
        #pragma unroll
        for (int off = 32; off; off >>= 1) sum += __shfl_xor(sum, off);
        const float fac = (float)smask[b * NS + s] / sum;
        const int4 im4 = *reinterpret_cast<const int4*>(imask + b * NR + lane * 4);
        wT[lane * 4 + 0][srel] = e.x * fac * (float)im4.x;
        wT[lane * 4 + 1][srel] = e.y * fac * (float)im4.y;
        wT[lane * 4 + 2][srel] = e.z * fac * (float)im4.z;
        wT[lane * 4 + 3][srel] = e.w * fac * (float)im4.w;
    }
    __syncthreads();
    float sumsq = 0.0f;
    const int txd = tid & 31;
    const int tys = tid >> 5;
    const float* Ib = image + (size_t)b * NR * DD;
    for (int dc = 0; dc < 8; ++dc) {
        const int d0 = dc * 128;
        float acc[4][4] = {};
        for (int rc = 0; rc < 8; ++rc) {
            const int r0 = rc * 32;
            {
                const int rr = tid >> 3;
                const int cb = tid & 7;
                const float* src = Ib + (size_t)(r0 + rr) * DD + d0;
                #pragma unroll
                for (int q = 0; q < 4; ++q)
                    *reinterpret_cast<float4*>(&Is[rr][(cb + 8 * q) * 4]) =
                        *reinterpret_cast<const float4*>(src + (cb + 8 * q) * 4);
            }
            __syncthreads();
            #pragma unroll 4
            for (int rr = 0; rr < 32; ++rr) {
                const float4 wv = *reinterpret_cast<const float4*>(&wT[r0 + rr][tys * 4]);
                const float4 iv = *reinterpret_cast<const float4*>(&Is[rr][txd * 4]);
                const float wvv[4] = {wv.x, wv.y, wv.z, wv.w};
                const float ivv[4] = {iv.x, iv.y, iv.z, iv.w};
                #pragma unroll
                for (int i = 0; i < 4; ++i)
                    #pragma unroll
                    for (int j = 0; j < 4; ++j)
                        acc[i][j] += wvv[i] * ivv[j];
            }
            __syncthreads();
        }
        #pragma unroll
        for (int i = 0; i < 4; ++i) {
            const int s = s0 + tys * 4 + i;
            const size_t base = ((size_t)b * NS + s) * DD + d0 + txd * 4;
            const float4 af = {acc[i][0], acc[i][1], acc[i][2], acc[i][3]};
            *reinterpret_cast<float4*>(att_first + base) = af;
            const float4 sp = *reinterpret_cast<const float4*>(span + base);
            float dx;
            dx = sp.x - af.x; sumsq += dx * dx;
            dx = sp.y - af.y; sumsq += dx * dx;
            dx = sp.z - af.z; sumsq += dx * dx;
            dx = sp.w - af.w; sumsq += dx * dx;
        }
    }
    red[tid] = sumsq; __syncthreads();
    for (int off = 128; off; off >>= 1) {
        if (tid < off) red[tid] += red[tid + off];
        __syncthreads();
    }
    if (tid == 0) atomicAdd(ws, (double)red[0]);
}

__global__ __launch_bounds__(256) void second_kernel(
    const float* __restrict__ span, const float* __restrict__ image,
    const int* __restrict__ smask, const int* __restrict__ imask,
    const float* __restrict__ att, double* __restrict__ ws) {
    const int b  = blockIdx.y;
    const int r0 = blockIdx.x * 32;
    __shared__ float w2s[32][36];
    __shared__ float Ss[32][132];
    __shared__ float mArr[32], fArr[32];
    __shared__ float redm[8][32];
    __shared__ float red[256];
    const int tid = threadIdx.x;
    const int rr = tid & 31, q = tid >> 5;
    const float* attb = att + (size_t)b * NS * NR + r0 + rr;
    float mloc = -3.4e38f;
    for (int t = 0; t < 64; ++t)
        mloc = fmaxf(mloc, attb[(size_t)(q * 64 + t) * NR]);
    redm[q][rr] = mloc;
    __syncthreads();
    if (tid < 32) {
        float m = redm[0][tid];
        #pragma unroll
        for (int qq = 1; qq < 8; ++qq) m = fmaxf(m, redm[qq][tid]);
        mArr[tid] = m;
    }
    __syncthreads();
    const float mcol = mArr[rr];
    float sloc = 0.0f;
    for (int t = 0; t < 64; ++t)
        sloc += expf(attb[(size_t)(q * 64 + t) * NR] - mcol);
    redm[q][rr] = sloc;
    __syncthreads();
    if (tid < 32) {
        float s = 0.0f;
        #pragma unroll
        for (int qq = 0; qq < 8; ++qq) s += redm[qq][tid];
        fArr[tid] = (float)imask[b * NR + r0 + tid] / s;
    }
    __syncthreads();
    float sumsq = 0.0f;
    const int txd = tid & 31;
    const int tyr = tid >> 5;
    const float* Sb = span + (size_t)b * NS * DD;
    for (int dc = 0; dc < 8; ++dc) {
        const int d0 = dc * 128;
        float acc[4][4] = {};
        for (int sc = 0; sc < 16; ++sc) {
            const int sb0 = sc * 32;
            {
                const int sr = tid >> 3;
                const int cb = tid & 7;
                const float* src = Sb + (size_t)(sb0 + sr) * DD + d0;
                #pragma unroll
                for (int qq = 0; qq < 4; ++qq)
                    *reinterpret_cast<float4*>(&Ss[sr][(cb + 8 * qq) * 4]) =
                        *reinterpret_cast<const float4*>(src + (cb + 8 * qq) * 4);
            }
            {
                const int ss = tid >> 3;
                const int rq = (tid & 7) * 4;
                const int s  = sb0 + ss;
                const float4 v = *reinterpret_cast<const float4*>(att + ((size_t)b * NS + s) * NR + r0 + rq);
                const float smv = (float)smask[b * NS + s];
                float4 wv;
                wv.x = expf(v.x - mArr[rq + 0]) * fArr[rq + 0] * smv;
                wv.y = expf(v.y - mArr[rq + 1]) * fArr[rq + 1] * smv;
                wv.z = expf(v.z - mArr[rq + 2]) * fArr[rq + 2] * smv;
                wv.w = expf(v.w - mArr[rq + 3]) * fArr[rq + 3] * smv;
                *reinterpret_cast<float4*>(&w2s[ss][rq]) = wv;
            }
            __syncthreads();
            #pragma unroll 4
            for (int ss = 0; ss < 32; ++ss) {
                const float4 wv = *reinterpret_cast<const float4*>(&w2s[ss][tyr * 4]);
                const float4 sv = *reinterpret_cast<const float4*>(&Ss[ss][txd * 4]);
                const float wvv[4] = {wv.x, wv.y, wv.z, wv.w};
                const float svv[4] = {sv.x, sv.y, sv.z, sv.w};
                #pragma unroll
                for (int i = 0; i < 4; ++i)
                    #pragma unroll
                    for (int j = 0; j < 4; ++j)
                        acc[i][j] += wvv[i] * svv[j];
            }
            __syncthreads();
        }
        #pragma unroll
        for (int i = 0; i < 4; ++i) {
            const int r = r0 + tyr * 4 + i;
            const float4 iv = *reinterpret_cast<const float4*>(image + ((size_t)b * NR + r) * DD + d0 + txd * 4);
            float dx;
            dx = iv.x - acc[i][0]; sumsq += dx * dx;
            dx = iv.y - acc[i][1]; sumsq += dx * dx;
            dx = iv.z - acc[i][2]; sumsq += dx * dx;
            dx = iv.w - acc[i][3]; sumsq += dx * dx;
        }
    }
    red[tid] = sumsq; __syncthreads();
    for (int off = 128; off; off >>= 1) {
        if (tid < off) red[tid] += red[tid + off];
        __syncthreads();
    }
    if (tid == 0) atomicAdd(ws + 1, (double)red[0]);
}

// ---------------------------------------------------------------- final score
__global__ __launch_bounds__(64) void score_kernel(const double* __restrict__ ws, float* __restrict__ out) {
    if (threadIdx.x == 0) {
        out[0] = (float)(ws[0] / (double)((size_t)B_ * NS * DD) +
                         ws[1] / (double)((size_t)B_ * NR * DD));
    }
}

extern "C" void kernel_launch(void* const* d_in, const int* in_sizes, int n_in,
                              void* d_out, int out_size, void* d_ws, size_t ws_size,
                              hipStream_t stream) {
    const float* span  = (const float*)d_in[0];
    const float* image = (const float*)d_in[1];
    const int*   smask = (const int*)d_in[2];
    const int*   imask = (const int*)d_in[3];
    float* out       = (float*)d_out;
    float* att_first = out + 1;
    float* att       = out + 1 + (size_t)B_ * NS * DD;
    double* wsum = (double*)d_ws;

    // ws layout for fast path
    float* m1 = (float*)((char*)d_ws + 512);
    float* f1 = m1 + B_ * NS;
    float* m2 = f1 + B_ * NS;
    float* f2 = m2 + B_ * NR;
    unsigned short* imgT = (unsigned short*)((char*)d_ws + 512 + 4 * (2 * B_ * NS + 2 * B_ * NR));
    unsigned short* spT  = imgT + (size_t)B_ * DD * NR;
    const size_t NEED = 512 + 4 * (size_t)(2 * B_ * NS + 2 * B_ * NR)
                      + 2 * ((size_t)B_ * DD * NR + (size_t)B_ * DD * NS);

    zero_ws<<<dim3(1), dim3(64), 0, stream>>>(wsum);
    att_mfma<<<dim3(NR / 128, NS / 128, B_), dim3(256), 0, stream>>>(span, image, smask, imask, att);

    if (ws_size >= NEED) {
        transpose_bf16<<<dim3(DD / 32, NR / 32, B_), dim3(256), 0, stream>>>(image, imgT, NR);
        transpose_bf16<<<dim3(DD / 32, NS / 32, B_), dim3(256), 0, stream>>>(span, spT, NS);
        stats_row<<<dim3(NS / 4, B_), dim3(256), 0, stream>>>(att, smask, m1, f1);
        stats_col<<<dim3(NR / 64, B_), dim3(256), 0, stream>>>(att, imask, m2, f2);
        first_mfma<<<dim3(DD / 256, NS / 64, B_), dim3(256), 0, stream>>>(span, imgT, imask, att, m1, f1, att_first, wsum);
        second_mfma<<<dim3(DD / 256, NR / 64, B_), dim3(256), 0, stream>>>(image, spT, smask, att, m2, f2, wsum);
    } else {
        first_kernel<<<dim3(NS / 32, B_), dim3(256), 0, stream>>>(span, image, smask, imask, att, att_first, wsum);
        second_kernel<<<dim3(NR / 32, B_), dim3(256), 0, stream>>>(span, image, smask, imask, att, wsum);
    }
    score_kernel<<<dim3(1), dim3(64), 0, stream>>>(wsum, out);
}

// Round 3
// 365.186 us; speedup vs baseline: 4.0831x; 1.2660x over previous
//
#include <hip/hip_runtime.h>
#include <hip/hip_bf16.h>
#include <math.h>

#define B_  64
#define NS  512
#define NR  256
#define DD  1024
#define NEGV (-1e10f)

typedef __attribute__((ext_vector_type(4))) float f32x4;
typedef __attribute__((ext_vector_type(8))) short bf16x8;

__device__ __forceinline__ unsigned short f2bf(float x) {
    unsigned u = __builtin_bit_cast(unsigned, x);
    unsigned r = u + 0x7FFFu + ((u >> 16) & 1u);
    return (unsigned short)(r >> 16);
}
// packed bf16 convert: D.lo = bf16(x), D.hi = bf16(y)
__device__ __forceinline__ unsigned pk2(float x, float y) {
    unsigned r;
    asm("v_cvt_pk_bf16_f32 %0, %1, %2" : "=v"(r) : "v"(x), "v"(y));
    return r;
}
__device__ __forceinline__ void pk_hilo(float x, float y, unsigned& h, unsigned& l) {
    h = pk2(x, y);
    const float hx = __builtin_bit_cast(float, h << 16);
    const float hy = __builtin_bit_cast(float, h & 0xFFFF0000u);
    l = pk2(x - hx, y - hy);
}
// async global->LDS, 16B per lane
__device__ __forceinline__ void gload16(const void* g, void* l) {
    __builtin_amdgcn_global_load_lds((const __attribute__((address_space(1))) void*)g,
                                     (__attribute__((address_space(3))) void*)l, 16, 0, 0);
}

// ---------------------------------------------------------------- zero ws
__global__ __launch_bounds__(64) void zero_ws(double* ws) {
    if (threadIdx.x == 0) { ws[0] = 0.0; ws[1] = 0.0; }
}

// ================================================================ stage 1
// att = masked span @ image^T, bf16 hi/lo split MFMA (3 passes), 128x128 tile
__global__ __launch_bounds__(256) void att_mfma(
    const float* __restrict__ span, const float* __restrict__ image,
    const int* __restrict__ smask, const int* __restrict__ imask,
    float* __restrict__ att) {
    const int b  = blockIdx.z;
    const int s0 = blockIdx.y * 128;
    const int r0 = blockIdx.x * 128;
    __shared__ unsigned short Ah[128][40], Al[128][40], Bh[128][40], Bl[128][40];
    const int tid  = threadIdx.x;
    const int lane = tid & 63;
    const int w    = tid >> 6;
    const int wso  = (w >> 1) * 64;
    const int wro  = (w & 1) * 64;
    const float* Sp = span  + ((size_t)b * NS + s0) * DD;
    const float* Im = image + ((size_t)b * NR + r0) * DD;

    f32x4 acc[4][4];
    #pragma unroll
    for (int i = 0; i < 4; ++i)
        #pragma unroll
        for (int j = 0; j < 4; ++j) acc[i][j] = (f32x4){0.f, 0.f, 0.f, 0.f};

    const int krel = (tid & 7) * 4;   // 0..28
    const int row0 = tid >> 3;        // 0..31
    const int fr   = lane & 15;
    const int fk   = (lane >> 4) * 8;

    for (int k0 = 0; k0 < DD; k0 += 32) {
        #pragma unroll
        for (int p = 0; p < 4; ++p) {
            const int row = row0 + p * 32;
            const float4 a = *reinterpret_cast<const float4*>(Sp + (size_t)row * DD + k0 + krel);
            const float4 c = *reinterpret_cast<const float4*>(Im + (size_t)row * DD + k0 + krel);
            unsigned h0, l0, h1, l1;
            pk_hilo(a.x, a.y, h0, l0); pk_hilo(a.z, a.w, h1, l1);
            uint2 u;
            u.x = h0; u.y = h1; *reinterpret_cast<uint2*>(&Ah[row][krel]) = u;
            u.x = l0; u.y = l1; *reinterpret_cast<uint2*>(&Al[row][krel]) = u;
            pk_hilo(c.x, c.y, h0, l0); pk_hilo(c.z, c.w, h1, l1);
            u.x = h0; u.y = h1; *reinterpret_cast<uint2*>(&Bh[row][krel]) = u;
            u.x = l0; u.y = l1; *reinterpret_cast<uint2*>(&Bl[row][krel]) = u;
        }
        __syncthreads();
        bf16x8 ah[4], al[4], bh[4], bl[4];
        #pragma unroll
        for (int mf = 0; mf < 4; ++mf) {
            ah[mf] = *reinterpret_cast<const bf16x8*>(&Ah[wso + mf * 16 + fr][fk]);
            al[mf] = *reinterpret_cast<const bf16x8*>(&Al[wso + mf * 16 + fr][fk]);
            bh[mf] = *reinterpret_cast<const bf16x8*>(&Bh[wro + mf * 16 + fr][fk]);
            bl[mf] = *reinterpret_cast<const bf16x8*>(&Bl[wro + mf * 16 + fr][fk]);
        }
        #pragma unroll
        for (int mf = 0; mf < 4; ++mf)
            #pragma unroll
            for (int nf = 0; nf < 4; ++nf) {
                acc[mf][nf] = __builtin_amdgcn_mfma_f32_16x16x32_bf16(ah[mf], bh[nf], acc[mf][nf], 0, 0, 0);
                acc[mf][nf] = __builtin_amdgcn_mfma_f32_16x16x32_bf16(ah[mf], bl[nf], acc[mf][nf], 0, 0, 0);
                acc[mf][nf] = __builtin_amdgcn_mfma_f32_16x16x32_bf16(al[mf], bh[nf], acc[mf][nf], 0, 0, 0);
            }
        __syncthreads();
    }
    const int fq = lane >> 4;
    int imv[4];
    #pragma unroll
    for (int nf = 0; nf < 4; ++nf) imv[nf] = imask[b * NR + r0 + wro + nf * 16 + fr];
    #pragma unroll
    for (int mf = 0; mf < 4; ++mf) {
        #pragma unroll
        for (int i = 0; i < 4; ++i) {
            const int s = s0 + wso + mf * 16 + fq * 4 + i;
            const int sm = smask[b * NS + s];
            float* orow = att + ((size_t)b * NS + s) * NR + r0 + wro;
            #pragma unroll
            for (int nf = 0; nf < 4; ++nf) {
                const float v = acc[mf][nf][i] * (float)(sm * imv[nf]);
                orow[nf * 16 + fr] = (v != 0.0f) ? v : NEGV;
            }
        }
    }
}

// ================================================================ transpose f32 -> bf16, K-swizzled: dst[b][d][chunk(n)*64 + ((n&63)^((d&7)<<3))]
__global__ __launch_bounds__(256) void transpose_swz(
    const float* __restrict__ src, unsigned short* __restrict__ dst, int N) {
    const int b = blockIdx.z, n0 = blockIdx.y * 32, d0 = blockIdx.x * 32;
    __shared__ unsigned short T[32][36];
    const int t = threadIdx.x;
    {
        const int n = t >> 3, dq = (t & 7) * 4;
        const float4 v = *reinterpret_cast<const float4*>(src + ((size_t)b * N + n0 + n) * DD + d0 + dq);
        T[dq + 0][n] = f2bf(v.x); T[dq + 1][n] = f2bf(v.y);
        T[dq + 2][n] = f2bf(v.z); T[dq + 3][n] = f2bf(v.w);
    }
    __syncthreads();
    {
        const int d = t >> 3, nq = (t & 7) * 4;
        const int dg = d0 + d;
        const int base = n0 + nq;
        const int pos = (base & 63) ^ ((dg & 7) << 3);
        const size_t idx = ((size_t)b * DD + dg) * N + (base & ~63) + pos;
        *reinterpret_cast<ushort4*>(dst + idx) = *reinterpret_cast<const ushort4*>(&T[d][nq]);
    }
}

// ================================================================ row softmax -> w1 bf16 (K-swizzled on r within 64-chunks by s&7)
__global__ __launch_bounds__(256) void statsrow_w1(
    const float* __restrict__ att, const int* __restrict__ smask,
    const int* __restrict__ imask, unsigned short* __restrict__ w1g) {
    const int b = blockIdx.y;
    const int s = blockIdx.x * 4 + (threadIdx.x >> 6);
    const int lane = threadIdx.x & 63;
    const float* row = att + ((size_t)b * NS + s) * NR;
    const float4 v = *reinterpret_cast<const float4*>(row + lane * 4);
    float m = fmaxf(fmaxf(v.x, v.y), fmaxf(v.z, v.w));
    #pragma unroll
    for (int off = 32; off; off >>= 1) m = fmaxf(m, __shfl_xor(m, off));
    const float e0 = expf(v.x - m), e1 = expf(v.y - m), e2 = expf(v.z - m), e3 = expf(v.w - m);
    float sum = e0 + e1 + e2 + e3;
    #pragma unroll
    for (int off = 32; off; off >>= 1) sum += __shfl_xor(sum, off);
    const float fac = (float)smask[b * NS + s] / sum;
    const int4 im4 = *reinterpret_cast<const int4*>(imask + b * NR + lane * 4);
    const unsigned p0 = pk2(e0 * fac * (float)im4.x, e1 * fac * (float)im4.y);
    const unsigned p1 = pk2(e2 * fac * (float)im4.z, e3 * fac * (float)im4.w);
    const int chunk = lane >> 4;
    const int cc = (lane & 15) * 4;
    const int pos = cc ^ ((s & 7) << 3);
    uint2 u; u.x = p0; u.y = p1;
    *reinterpret_cast<uint2*>(w1g + ((size_t)b * NS + s) * NR + chunk * 64 + pos) = u;
}

// ================================================================ column softmax stats (m2, f2 = imask/sum)
__global__ __launch_bounds__(256) void stats_col(
    const float* __restrict__ att, const int* __restrict__ imask,
    float* __restrict__ m2, float* __restrict__ f2) {
    const int b = blockIdx.y, r0 = blockIdx.x * 64;
    const int tid = threadIdx.x, c = tid & 63, q = tid >> 6;
    __shared__ float red[4][64];
    __shared__ float mcol[64];
    const float* base = att + (size_t)b * NS * NR + r0 + c;
    float m = -3.4e38f;
    for (int s = q; s < NS; s += 4) m = fmaxf(m, base[(size_t)s * NR]);
    red[q][c] = m;
    __syncthreads();
    if (tid < 64) mcol[tid] = fmaxf(fmaxf(red[0][tid], red[1][tid]), fmaxf(red[2][tid], red[3][tid]));
    __syncthreads();
    const float mc = mcol[c];
    float ssum = 0.0f;
    for (int s = q; s < NS; s += 4) ssum += expf(base[(size_t)s * NR] - mc);
    red[q][c] = ssum;
    __syncthreads();
    if (tid < 64) {
        const float tot = red[0][tid] + red[1][tid] + red[2][tid] + red[3][tid];
        m2[b * NR + r0 + tid] = mcol[tid];
        f2[b * NR + r0 + tid] = (float)imask[b * NR + r0 + tid] / tot;
    }
}

// ================================================================ w2[b][r][s] bf16 (K-swizzled on s by r&7) via LDS transpose
__global__ __launch_bounds__(256) void build_w2k(
    const float* __restrict__ att, const int* __restrict__ smask,
    const float* __restrict__ m2, const float* __restrict__ f2,
    unsigned short* __restrict__ w2g) {
    const int b = blockIdx.z, s0 = blockIdx.y * 64, r0 = blockIdx.x * 64;
    __shared__ unsigned short T[64][68];
    __shared__ float m2s[64], f2s[64], sms[64];
    const int tid = threadIdx.x;
    if (tid < 64) {
        m2s[tid] = m2[b * NR + r0 + tid];
        f2s[tid] = f2[b * NR + r0 + tid];
        sms[tid] = (float)smask[b * NS + s0 + tid];
    }
    __syncthreads();
    {
        const int ss = tid >> 2, rg = (tid & 3) * 16;
        const float smv = sms[ss];
        const float* arow = att + ((size_t)b * NS + s0 + ss) * NR + r0 + rg;
        #pragma unroll
        for (int g = 0; g < 4; ++g) {
            const float4 v = *reinterpret_cast<const float4*>(arow + g * 4);
            const int rb = rg + g * 4;
            T[rb + 0][ss] = f2bf(expf(v.x - m2s[rb + 0]) * f2s[rb + 0] * smv);
            T[rb + 1][ss] = f2bf(expf(v.y - m2s[rb + 1]) * f2s[rb + 1] * smv);
            T[rb + 2][ss] = f2bf(expf(v.z - m2s[rb + 2]) * f2s[rb + 2] * smv);
            T[rb + 3][ss] = f2bf(expf(v.w - m2s[rb + 3]) * f2s[rb + 3] * smv);
        }
    }
    __syncthreads();
    {
        const int rl = tid >> 2, sg = (tid & 3) * 16;
        const int swz = (rl & 7) << 3;
        const size_t rowb = ((size_t)b * NR + r0 + rl) * NS + s0;
        const int out16 = sg ^ (swz & 48);
        #pragma unroll
        for (int g = 0; g < 4; ++g) {
            const int pos = out16 + ((g * 4) ^ (swz & 8));
            *reinterpret_cast<ushort4*>(w2g + rowb + pos) =
                *reinterpret_cast<const ushort4*>(&T[rl][sg + g * 4]);
        }
    }
}

// ================================================================ apply GEMM: C[64 m x 256 d] = A[m][K] @ Bt[d][K] (both pre-swizzled bf16)
// + MSE vs ref, optional C write. m97-style: global_load_lds + swizzled ds_read.
template<int KTOT, int MT, bool WOUT, int WIDX>
__global__ __launch_bounds__(256) void gemm_apply(
    const unsigned short* __restrict__ Ag, const unsigned short* __restrict__ Btg,
    const float* __restrict__ ref, float* __restrict__ outp, double* __restrict__ wsum) {
    const int b = blockIdx.z, m0 = blockIdx.y * 64, d0 = blockIdx.x * 256;
    __shared__ unsigned short As[64 * 64];
    __shared__ unsigned short Bs[256 * 64];
    __shared__ float redsum[256];
    const int tid = threadIdx.x, lane = tid & 63, w = tid >> 6;
    const int fr = lane & 15, fq = lane >> 4;
    f32x4 acc[4][4];
    #pragma unroll
    for (int i = 0; i < 4; ++i)
        #pragma unroll
        for (int j = 0; j < 4; ++j) acc[i][j] = (f32x4){0.f, 0.f, 0.f, 0.f};

    const int srow = tid >> 3;             // 0..31 staging row
    const int scol = (tid & 7) * 16;       // byte offset in 128B chunk
    for (int kc = 0; kc < KTOT / 64; ++kc) {
        const char* asrc = (const char*)(Ag + ((size_t)b * MT + m0) * KTOT) + kc * 128 + scol;
        #pragma unroll
        for (int c = 0; c < 2; ++c)
            gload16(asrc + (size_t)(c * 32 + srow) * (KTOT * 2), (char*)As + (c * 256 + tid) * 16);
        const char* bsrc = (const char*)(Btg + ((size_t)b * DD + d0) * KTOT) + kc * 128 + scol;
        #pragma unroll
        for (int c = 0; c < 8; ++c)
            gload16(bsrc + (size_t)(c * 32 + srow) * (KTOT * 2), (char*)Bs + (c * 256 + tid) * 16);
        __syncthreads();
        #pragma unroll
        for (int ks = 0; ks < 2; ++ks) {
            bf16x8 aF[4], bF[4];
            #pragma unroll
            for (int mf = 0; mf < 4; ++mf) {
                const int row = mf * 16 + fr;
                const int pos = (ks * 32 + fq * 8) ^ ((row & 7) << 3);
                aF[mf] = *reinterpret_cast<const bf16x8*>(&As[row * 64 + pos]);
            }
            #pragma unroll
            for (int nf = 0; nf < 4; ++nf) {
                const int row = w * 64 + nf * 16 + fr;
                const int pos = (ks * 32 + fq * 8) ^ ((row & 7) << 3);
                bF[nf] = *reinterpret_cast<const bf16x8*>(&Bs[row * 64 + pos]);
            }
            #pragma unroll
            for (int mf = 0; mf < 4; ++mf)
                #pragma unroll
                for (int nf = 0; nf < 4; ++nf)
                    acc[mf][nf] = __builtin_amdgcn_mfma_f32_16x16x32_bf16(aF[mf], bF[nf], acc[mf][nf], 0, 0, 0);
        }
        __syncthreads();
    }
    float sumsq = 0.0f;
    #pragma unroll
    for (int mf = 0; mf < 4; ++mf) {
        #pragma unroll
        for (int i = 0; i < 4; ++i) {
            const int row = m0 + mf * 16 + fq * 4 + i;
            const size_t base = ((size_t)b * MT + row) * DD + d0 + w * 64;
            #pragma unroll
            for (int nf = 0; nf < 4; ++nf) {
                const float v = acc[mf][nf][i];
                const float rv = ref[base + nf * 16 + fr];
                if constexpr (WOUT) outp[base + nf * 16 + fr] = v;
                const float dx = rv - v;
                sumsq += dx * dx;
            }
        }
    }
    redsum[tid] = sumsq; __syncthreads();
    for (int off = 128; off; off >>= 1) {
        if (tid < off) redsum[tid] += redsum[tid + off];
        __syncthreads();
    }
    if (tid == 0) atomicAdd(wsum + WIDX, (double)redsum[0]);
}

// ================================================================ fallback f32 kernels (used when ws too small)
__global__ __launch_bounds__(256) void first_kernel(
    const float* __restrict__ span, const float* __restrict__ image,
    const int* __restrict__ smask, const int* __restrict__ imask,
    const float* __restrict__ att, float* __restrict__ att_first,
    double* __restrict__ ws) {
    const int b  = blockIdx.y;
    const int s0 = blockIdx.x * 32;
    __shared__ float wT[256][36];
    __shared__ float Is[32][132];
    __shared__ float red[256];
    const int tid  = threadIdx.x;
    const int lane = tid & 63, wave = tid >> 6;
    for (int i = 0; i < 8; ++i) {
        const int srel = wave * 8 + i;
        const int s    = s0 + srel;
        const float4 v = *reinterpret_cast<const float4*>(att + ((size_t)b * NS + s) * NR + lane * 4);
        float m = fmaxf(fmaxf(v.x, v.y), fmaxf(v.z, v.w));
        #pragma unroll
        for (int off = 32; off; off >>= 1) m = fmaxf(m, __shfl_xor(m, off));
        float4 e;
        e.x = expf(v.x - m); e.y = expf(v.y - m); e.z = expf(v.z - m); e.w = expf(v.w - m);
        float sum = e.x + e.y + e.z + e.w;
        #pragma unroll
        for (int off = 32; off; off >>= 1) sum += __shfl_xor(sum, off);
        const float fac = (float)smask[b * NS + s] / sum;
        const int4 im4 = *reinterpret_cast<const int4*>(imask + b * NR + lane * 4);
        wT[lane * 4 + 0][srel] = e.x * fac * (float)im4.x;
        wT[lane * 4 + 1][srel] = e.y * fac * (float)im4.y;
        wT[lane * 4 + 2][srel] = e.z * fac * (float)im4.z;
        wT[lane * 4 + 3][srel] = e.w * fac * (float)im4.w;
    }
    __syncthreads();
    float sumsq = 0.0f;
    const int txd = tid & 31;
    const int tys = tid >> 5;
    const float* Ib = image + (size_t)b * NR * DD;
    for (int dc = 0; dc < 8; ++dc) {
        const int d0 = dc * 128;
        float acc[4][4] = {};
        for (int rc = 0; rc < 8; ++rc) {
            const int r0 = rc * 32;
            {
                const int rr = tid >> 3;
                const int cb = tid & 7;
                const float* src = Ib + (size_t)(r0 + rr) * DD + d0;
                #pragma unroll
                for (int q = 0; q < 4; ++q)
                    *reinterpret_cast<float4*>(&Is[rr][(cb + 8 * q) * 4]) =
                        *reinterpret_cast<const float4*>(src + (cb + 8 * q) * 4);
            }
            __syncthreads();
            #pragma unroll 4
            for (int rr = 0; rr < 32; ++rr) {
                const float4 wv = *reinterpret_cast<const float4*>(&wT[r0 + rr][tys * 4]);
                const float4 iv = *reinterpret_cast<const float4*>(&Is[rr][txd * 4]);
                const float wvv[4] = {wv.x, wv.y, wv.z, wv.w};
                const float ivv[4] = {iv.x, iv.y, iv.z, iv.w};
                #pragma unroll
                for (int i = 0; i < 4; ++i)
                    #pragma unroll
                    for (int j = 0; j < 4; ++j)
                        acc[i][j] += wvv[i] * ivv[j];
            }
            __syncthreads();
        }
        #pragma unroll
        for (int i = 0; i < 4; ++i) {
            const int s = s0 + tys * 4 + i;
            const size_t base = ((size_t)b * NS + s) * DD + d0 + txd * 4;
            const float4 af = {acc[i][0], acc[i][1], acc[i][2], acc[i][3]};
            *reinterpret_cast<float4*>(att_first + base) = af;
            const float4 sp = *reinterpret_cast<const float4*>(span + base);
            float dx;
            dx = sp.x - af.x; sumsq += dx * dx;
            dx = sp.y - af.y; sumsq += dx * dx;
            dx = sp.z - af.z; sumsq += dx * dx;
            dx = sp.w - af.w; sumsq += dx * dx;
        }
    }
    red[tid] = sumsq; __syncthreads();
    for (int off = 128; off; off >>= 1) {
        if (tid < off) red[tid] += red[tid + off];
        __syncthreads();
    }
    if (tid == 0) atomicAdd(ws, (double)red[0]);
}

__global__ __launch_bounds__(256) void second_kernel(
    const float* __restrict__ span, const float* __restrict__ image,
    const int* __restrict__ smask, const int* __restrict__ imask,
    const float* __restrict__ att, double* __restrict__ ws) {
    const int b  = blockIdx.y;
    const int r0 = blockIdx.x * 32;
    __shared__ float w2s[32][36];
    __shared__ float Ss[32][132];
    __shared__ float mArr[32], fArr[32];
    __shared__ float redm[8][32];
    __shared__ float red[256];
    const int tid = threadIdx.x;
    const int rr = tid & 31, q = tid >> 5;
    const float* attb = att + (size_t)b * NS * NR + r0 + rr;
    float mloc = -3.4e38f;
    for (int t = 0; t < 64; ++t)
        mloc = fmaxf(mloc, attb[(size_t)(q * 64 + t) * NR]);
    redm[q][rr] = mloc;
    __syncthreads();
    if (tid < 32) {
        float m = redm[0][tid];
        #pragma unroll
        for (int qq = 1; qq < 8; ++qq) m = fmaxf(m, redm[qq][tid]);
        mArr[tid] = m;
    }
    __syncthreads();
    const float mcol = mArr[rr];
    float sloc = 0.0f;
    for (int t = 0; t < 64; ++t)
        sloc += expf(attb[(size_t)(q * 64 + t) * NR] - mcol);
    redm[q][rr] = sloc;
    __syncthreads();
    if (tid < 32) {
        float s = 0.0f;
        #pragma unroll
        for (int qq = 0; qq < 8; ++qq) s += redm[qq][tid];
        fArr[tid] = (float)imask[b * NR + r0 + tid] / s;
    }
    __syncthreads();
    float sumsq = 0.0f;
    const int txd = tid & 31;
    const int tyr = tid >> 5;
    const float* Sb = span + (size_t)b * NS * DD;
    for (int dc = 0; dc < 8; ++dc) {
        const int d0 = dc * 128;
        float acc[4][4] = {};
        for (int sc = 0; sc < 16; ++sc) {
            const int sb0 = sc * 32;
            {
                const int sr = tid >> 3;
                const int cb = tid & 7;
                const float* src = Sb + (size_t)(sb0 + sr) * DD + d0;
                #pragma unroll
                for (int qq = 0; qq < 4; ++qq)
                    *reinterpret_cast<float4*>(&Ss[sr][(cb + 8 * qq) * 4]) =
                        *reinterpret_cast<const float4*>(src + (cb + 8 * qq) * 4);
            }
            {
                const int ss = tid >> 3;
                const int rq = (tid & 7) * 4;
                const int s  = sb0 + ss;
                const float4 v = *reinterpret_cast<const float4*>(att + ((size_t)b * NS + s) * NR + r0 + rq);
                const float smv = (float)smask[b * NS + s];
                float4 wv;
                wv.x = expf(v.x - mArr[rq + 0]) * fArr[rq + 0] * smv;
                wv.y = expf(v.y - mArr[rq + 1]) * fArr[rq + 1] * smv;
                wv.z = expf(v.z - mArr[rq + 2]) * fArr[rq + 2] * smv;
                wv.w = expf(v.w - mArr[rq + 3]) * fArr[rq + 3] * smv;
                *reinterpret_cast<float4*>(&w2s[ss][rq]) = wv;
            }
            __syncthreads();
            #pragma unroll 4
            for (int ss = 0; ss < 32; ++ss) {
                const float4 wv = *reinterpret_cast<const float4*>(&w2s[ss][tyr * 4]);
                const float4 sv = *reinterpret_cast<const float4*>(&Ss[ss][txd * 4]);
                const float wvv[4] = {wv.x, wv.y, wv.z, wv.w};
                const float svv[4] = {sv.x, sv.y, sv.z, sv.w};
                #pragma unroll
                for (int i = 0; i < 4; ++i)
                    #pragma unroll
                    for (int j = 0; j < 4; ++j)
                        acc[i][j] += wvv[i] * svv[j];
            }
            __syncthreads();
        }
        #pragma unroll
        for (int i = 0; i < 4; ++i) {
            const int r = r0 + tyr * 4 + i;
            const float4 iv = *reinterpret_cast<const float4*>(image + ((size_t)b * NR + r) * DD + d0 + txd * 4);
            float dx;
            dx = iv.x - acc[i][0]; sumsq += dx * dx;
            dx = iv.y - acc[i][1]; sumsq += dx * dx;
            dx = iv.z - acc[i][2]; sumsq += dx * dx;
            dx = iv.w - acc[i][3]; sumsq += dx * dx;
        }
    }
    red[tid] = sumsq; __syncthreads();
    for (int off = 128; off; off >>= 1) {
        if (tid < off) red[tid] += red[tid + off];
        __syncthreads();
    }
    if (tid == 0) atomicAdd(ws + 1, (double)red[0]);
}

// ---------------------------------------------------------------- final score
__global__ __launch_bounds__(64) void score_kernel(const double* __restrict__ ws, float* __restrict__ out) {
    if (threadIdx.x == 0) {
        out[0] = (float)(ws[0] / (double)((size_t)B_ * NS * DD) +
                         ws[1] / (double)((size_t)B_ * NR * DD));
    }
}

extern "C" void kernel_launch(void* const* d_in, const int* in_sizes, int n_in,
                              void* d_out, int out_size, void* d_ws, size_t ws_size,
                              hipStream_t stream) {
    const float* span  = (const float*)d_in[0];
    const float* image = (const float*)d_in[1];
    const int*   smask = (const int*)d_in[2];
    const int*   imask = (const int*)d_in[3];
    float* out       = (float*)d_out;
    float* att_first = out + 1;
    float* att       = out + 1 + (size_t)B_ * NS * DD;
    double* wsum = (double*)d_ws;

    // ws layout (phased):
    //   [0,512)                 wsum
    //   [512, +64*256*4)        m2
    //   [.. , +64*256*4)        f2
    //   X0: phase1 = { w1 (16.78MB), imgT (33.55MB) }
    //       phase2 = { spT (67.1MB), w2 (16.78MB) }   (overwrites phase1)
    char* base = (char*)d_ws;
    float* m2 = (float*)(base + 512);
    float* f2 = (float*)(base + 512 + (size_t)B_ * NR * 4);
    char*  X0 = base + 512 + 2 * (size_t)B_ * NR * 4;
    unsigned short* w1g  = (unsigned short*)X0;
    unsigned short* imgT = (unsigned short*)(X0 + (size_t)B_ * NS * NR * 2);
    unsigned short* spT  = (unsigned short*)X0;
    unsigned short* w2g  = (unsigned short*)(X0 + (size_t)B_ * DD * NS * 2);
    const size_t NEED = 512 + 2 * (size_t)B_ * NR * 4
                      + (size_t)B_ * DD * NS * 2 + (size_t)B_ * NR * NS * 2;

    zero_ws<<<dim3(1), dim3(64), 0, stream>>>(wsum);
    att_mfma<<<dim3(NR / 128, NS / 128, B_), dim3(256), 0, stream>>>(span, image, smask, imask, att);

    if (ws_size >= NEED) {
        // phase 1: first attention apply
        stats_col<<<dim3(NR / 64, B_), dim3(256), 0, stream>>>(att, imask, m2, f2);
        statsrow_w1<<<dim3(NS / 4, B_), dim3(256), 0, stream>>>(att, smask, imask, w1g);
        transpose_swz<<<dim3(DD / 32, NR / 32, B_), dim3(256), 0, stream>>>(image, imgT, NR);
        gemm_apply<NR, NS, true, 0><<<dim3(DD / 256, NS / 64, B_), dim3(256), 0, stream>>>(
            w1g, imgT, span, att_first, wsum);
        // phase 2: second attention apply (reuses X0 region)
        transpose_swz<<<dim3(DD / 32, NS / 32, B_), dim3(256), 0, stream>>>(span, spT, NS);
        build_w2k<<<dim3(NR / 64, NS / 64, B_), dim3(256), 0, stream>>>(att, smask, m2, f2, w2g);
        gemm_apply<NS, NR, false, 1><<<dim3(DD / 256, NR / 64, B_), dim3(256), 0, stream>>>(
            w2g, spT, image, nullptr, wsum);
    } else {
        first_kernel<<<dim3(NS / 32, B_), dim3(256), 0, stream>>>(span, image, smask, imask, att, att_first, wsum);
        second_kernel<<<dim3(NR / 32, B_), dim3(256), 0, stream>>>(span, image, smask, imask, att, wsum);
    }
    score_kernel<<<dim3(1), dim3(64), 0, stream>>>(wsum, out);
}

// Round 4
// 306.094 us; speedup vs baseline: 4.8713x; 1.1931x over previous
//
#include <hip/hip_runtime.h>
#include <hip/hip_bf16.h>
#include <math.h>

#define B_  64
#define NS  512
#define NR  256
#define DD  1024
#define NEGV (-1e10f)

typedef __attribute__((ext_vector_type(4))) float f32x4;
typedef __attribute__((ext_vector_type(8))) short bf16x8;

__device__ __forceinline__ unsigned short f2bf(float x) {
    unsigned u = __builtin_bit_cast(unsigned, x);
    unsigned r = u + 0x7FFFu + ((u >> 16) & 1u);
    return (unsigned short)(r >> 16);
}
// packed bf16 convert: D.lo = bf16(x), D.hi = bf16(y)
__device__ __forceinline__ unsigned pk2(float x, float y) {
    unsigned r;
    asm("v_cvt_pk_bf16_f32 %0, %1, %2" : "=v"(r) : "v"(x), "v"(y));
    return r;
}
__device__ __forceinline__ void pk_hilo(float x, float y, unsigned& h, unsigned& l) {
    h = pk2(x, y);
    const float hx = __builtin_bit_cast(float, h << 16);
    const float hy = __builtin_bit_cast(float, h & 0xFFFF0000u);
    l = pk2(x - hx, y - hy);
}
// async global->LDS, 16B per lane
__device__ __forceinline__ void gload16(const void* g, void* l) {
    __builtin_amdgcn_global_load_lds((const __attribute__((address_space(1))) void*)g,
                                     (__attribute__((address_space(3))) void*)l, 16, 0, 0);
}

// ---------------------------------------------------------------- zero ws
__global__ __launch_bounds__(64) void zero_ws(double* ws) {
    if (threadIdx.x == 0) { ws[0] = 0.0; ws[1] = 0.0; }
}

// ================================================================ stage 1
// att = masked span @ image^T, bf16 hi/lo 3-pass MFMA, 128x128 tile,
// VGPR-prefetch staging (T14) + fused partial softmax stats (row & col).
__global__ __launch_bounds__(256) void att_mfma(
    const float* __restrict__ span, const float* __restrict__ image,
    const int* __restrict__ smask, const int* __restrict__ imask,
    float* __restrict__ att, float2* __restrict__ rowP, float2* __restrict__ colP,
    int doStats) {
    const int b  = blockIdx.z;
    const int s0 = blockIdx.y * 128;
    const int r0 = blockIdx.x * 128;
    __shared__ unsigned short Ah[128][40], Al[128][40], Bh[128][40], Bl[128][40];
    __shared__ float2 rowLDS[128][2];
    __shared__ float2 colLDS[128][2];
    const int tid  = threadIdx.x;
    const int lane = tid & 63;
    const int w    = tid >> 6;
    const int wso  = (w >> 1) * 64;
    const int wro  = (w & 1) * 64;
    const float* Sp = span  + ((size_t)b * NS + s0) * DD;
    const float* Im = image + ((size_t)b * NR + r0) * DD;

    f32x4 acc[4][4];
    #pragma unroll
    for (int i = 0; i < 4; ++i)
        #pragma unroll
        for (int j = 0; j < 4; ++j) acc[i][j] = (f32x4){0.f, 0.f, 0.f, 0.f};

    const int krel = (tid & 7) * 4;   // 0..28
    const int row0 = tid >> 3;        // 0..31
    const int fr   = lane & 15;
    const int fk   = (lane >> 4) * 8;

    float4 pa[4], pc[4];
    auto LOADK = [&](int k0) {
        #pragma unroll
        for (int p = 0; p < 4; ++p) {
            const int row = row0 + p * 32;
            pa[p] = *reinterpret_cast<const float4*>(Sp + (size_t)row * DD + k0 + krel);
            pc[p] = *reinterpret_cast<const float4*>(Im + (size_t)row * DD + k0 + krel);
        }
    };
    auto CONVW = [&]() {
        #pragma unroll
        for (int p = 0; p < 4; ++p) {
            const int row = row0 + p * 32;
            unsigned h0, l0, h1, l1;
            uint2 u;
            pk_hilo(pa[p].x, pa[p].y, h0, l0); pk_hilo(pa[p].z, pa[p].w, h1, l1);
            u.x = h0; u.y = h1; *reinterpret_cast<uint2*>(&Ah[row][krel]) = u;
            u.x = l0; u.y = l1; *reinterpret_cast<uint2*>(&Al[row][krel]) = u;
            pk_hilo(pc[p].x, pc[p].y, h0, l0); pk_hilo(pc[p].z, pc[p].w, h1, l1);
            u.x = h0; u.y = h1; *reinterpret_cast<uint2*>(&Bh[row][krel]) = u;
            u.x = l0; u.y = l1; *reinterpret_cast<uint2*>(&Bl[row][krel]) = u;
        }
    };
    auto FRAGMFMA = [&]() {
        bf16x8 ah[4], al[4], bh[4], bl[4];
        #pragma unroll
        for (int mf = 0; mf < 4; ++mf) {
            ah[mf] = *reinterpret_cast<const bf16x8*>(&Ah[wso + mf * 16 + fr][fk]);
            al[mf] = *reinterpret_cast<const bf16x8*>(&Al[wso + mf * 16 + fr][fk]);
            bh[mf] = *reinterpret_cast<const bf16x8*>(&Bh[wro + mf * 16 + fr][fk]);
            bl[mf] = *reinterpret_cast<const bf16x8*>(&Bl[wro + mf * 16 + fr][fk]);
        }
        #pragma unroll
        for (int mf = 0; mf < 4; ++mf)
            #pragma unroll
            for (int nf = 0; nf < 4; ++nf) {
                acc[mf][nf] = __builtin_amdgcn_mfma_f32_16x16x32_bf16(ah[mf], bh[nf], acc[mf][nf], 0, 0, 0);
                acc[mf][nf] = __builtin_amdgcn_mfma_f32_16x16x32_bf16(ah[mf], bl[nf], acc[mf][nf], 0, 0, 0);
                acc[mf][nf] = __builtin_amdgcn_mfma_f32_16x16x32_bf16(al[mf], bh[nf], acc[mf][nf], 0, 0, 0);
            }
    };

    LOADK(0); CONVW(); __syncthreads();
    for (int kt = 0; kt < 31; ++kt) {
        LOADK((kt + 1) * 32);     // in flight across the MFMA phase
        FRAGMFMA();
        __syncthreads();
        CONVW();
        __syncthreads();
    }
    FRAGMFMA();

    // ---- epilogue: mask + zero->NEG store, fused partial softmax stats
    const int fq = lane >> 4;
    float imvf[4];
    #pragma unroll
    for (int nf = 0; nf < 4; ++nf) imvf[nf] = (float)imask[b * NR + r0 + wro + nf * 16 + fr];
    float cmax[4] = {-3.4e38f, -3.4e38f, -3.4e38f, -3.4e38f};
    float smv[4][4];
    #pragma unroll
    for (int mf = 0; mf < 4; ++mf) {
        #pragma unroll
        for (int i = 0; i < 4; ++i) {
            const int s = s0 + wso + mf * 16 + fq * 4 + i;
            const float sv = (float)smask[b * NS + s];
            smv[mf][i] = sv;
            float* orow = att + ((size_t)b * NS + s) * NR + r0 + wro;
            float vj[4];
            #pragma unroll
            for (int nf = 0; nf < 4; ++nf) {
                float v = acc[mf][nf][i] * (sv * imvf[nf]);
                v = (v != 0.0f) ? v : NEGV;
                orow[nf * 16 + fr] = v;
                vj[nf] = v;
                cmax[nf] = fmaxf(cmax[nf], v);
            }
            if (doStats) {
                float rm = fmaxf(fmaxf(vj[0], vj[1]), fmaxf(vj[2], vj[3]));
                rm = fmaxf(rm, __shfl_xor(rm, 1));
                rm = fmaxf(rm, __shfl_xor(rm, 2));
                rm = fmaxf(rm, __shfl_xor(rm, 4));
                rm = fmaxf(rm, __shfl_xor(rm, 8));
                float rs = expf(vj[0] - rm) + expf(vj[1] - rm) + expf(vj[2] - rm) + expf(vj[3] - rm);
                rs += __shfl_xor(rs, 1);
                rs += __shfl_xor(rs, 2);
                rs += __shfl_xor(rs, 4);
                rs += __shfl_xor(rs, 8);
                if (fr == 0) rowLDS[wso + mf * 16 + fq * 4 + i][w & 1] = make_float2(rm, rs);
            }
        }
    }
    if (doStats) {
        #pragma unroll
        for (int nf = 0; nf < 4; ++nf) {
            cmax[nf] = fmaxf(cmax[nf], __shfl_xor(cmax[nf], 16));
            cmax[nf] = fmaxf(cmax[nf], __shfl_xor(cmax[nf], 32));
        }
        float csum[4] = {0.f, 0.f, 0.f, 0.f};
        #pragma unroll
        for (int mf = 0; mf < 4; ++mf)
            #pragma unroll
            for (int i = 0; i < 4; ++i)
                #pragma unroll
                for (int nf = 0; nf < 4; ++nf) {
                    float v = acc[mf][nf][i] * (smv[mf][i] * imvf[nf]);
                    v = (v != 0.0f) ? v : NEGV;
                    csum[nf] += expf(v - cmax[nf]);
                }
        #pragma unroll
        for (int nf = 0; nf < 4; ++nf) {
            csum[nf] += __shfl_xor(csum[nf], 16);
            csum[nf] += __shfl_xor(csum[nf], 32);
        }
        if (lane < 16) {
            #pragma unroll
            for (int nf = 0; nf < 4; ++nf)
                colLDS[wro + nf * 16 + lane][w >> 1] = make_float2(cmax[nf], csum[nf]);
        }
        __syncthreads();
        if (tid < 128) {
            const float2 q0 = rowLDS[tid][0], q1 = rowLDS[tid][1];
            const float m = fmaxf(q0.x, q1.x);
            const float ssum = q0.y * expf(q0.x - m) + q1.y * expf(q1.x - m);
            rowP[((size_t)b * NS + s0 + tid) * 2 + blockIdx.x] = make_float2(m, ssum);
        } else {
            const int c = tid - 128;
            const float2 q0 = colLDS[c][0], q1 = colLDS[c][1];
            const float m = fmaxf(q0.x, q1.x);
            const float ssum = q0.y * expf(q0.x - m) + q1.y * expf(q1.x - m);
            colP[((size_t)b * NR + r0 + c) * 4 + blockIdx.y] = make_float2(m, ssum);
        }
    }
}

// ================================================================ combine partials -> m1,f1 (rows), m2,f2 (cols)
__global__ __launch_bounds__(256) void combine_stats(
    const float2* __restrict__ rowP, const float2* __restrict__ colP,
    const int* __restrict__ smask, const int* __restrict__ imask,
    float* __restrict__ m1, float* __restrict__ f1,
    float* __restrict__ m2, float* __restrict__ f2) {
    const int idx = blockIdx.x * 256 + threadIdx.x;
    if (idx < B_ * NS) {
        const float2 p0 = rowP[(size_t)idx * 2 + 0];
        const float2 p1 = rowP[(size_t)idx * 2 + 1];
        const float m = fmaxf(p0.x, p1.x);
        const float s = p0.y * expf(p0.x - m) + p1.y * expf(p1.x - m);
        m1[idx] = m;
        f1[idx] = (float)smask[idx] / s;
    } else if (idx < B_ * NS + B_ * NR) {
        const int j = idx - B_ * NS;
        const float2 p0 = colP[(size_t)j * 4 + 0];
        const float2 p1 = colP[(size_t)j * 4 + 1];
        const float2 p2 = colP[(size_t)j * 4 + 2];
        const float2 p3 = colP[(size_t)j * 4 + 3];
        const float m = fmaxf(fmaxf(p0.x, p1.x), fmaxf(p2.x, p3.x));
        const float s = p0.y * expf(p0.x - m) + p1.y * expf(p1.x - m)
                      + p2.y * expf(p2.x - m) + p3.y * expf(p3.x - m);
        m2[j] = m;
        f2[j] = (float)imask[j] / s;
    }
}

// ================================================================ transpose f32 -> bf16, K-swizzled within 64-chunks by (d&7)<<3
__global__ __launch_bounds__(256) void transpose_swz(
    const float* __restrict__ src, unsigned short* __restrict__ dst, int N) {
    const int b = blockIdx.z, n0 = blockIdx.y * 32, d0 = blockIdx.x * 32;
    __shared__ unsigned short T[32][36];
    const int t = threadIdx.x;
    {
        const int n = t >> 3, dq = (t & 7) * 4;
        const float4 v = *reinterpret_cast<const float4*>(src + ((size_t)b * N + n0 + n) * DD + d0 + dq);
        T[dq + 0][n] = f2bf(v.x); T[dq + 1][n] = f2bf(v.y);
        T[dq + 2][n] = f2bf(v.z); T[dq + 3][n] = f2bf(v.w);
    }
    __syncthreads();
    {
        const int d = t >> 3, nq = (t & 7) * 4;
        const int dg = d0 + d;
        const int base = n0 + nq;
        const int pos = (base & 63) ^ ((dg & 7) << 3);
        const size_t idx = ((size_t)b * DD + dg) * N + (base & ~63) + pos;
        *reinterpret_cast<ushort4*>(dst + idx) = *reinterpret_cast<const ushort4*>(&T[d][nq]);
    }
}

// ================================================================ build w1 ([s][r], swizzled) AND w2 ([r][s], swizzled) in one att pass
__global__ __launch_bounds__(256) void build_w12(
    const float* __restrict__ att, const int* __restrict__ smask,
    const int* __restrict__ imask,
    const float* __restrict__ m1, const float* __restrict__ f1,
    const float* __restrict__ m2, const float* __restrict__ f2,
    unsigned short* __restrict__ w1g, unsigned short* __restrict__ w2g) {
    const int b = blockIdx.z, s0 = blockIdx.y * 64, r0 = blockIdx.x * 64;
    __shared__ unsigned short T[64][68];
    __shared__ float m2s[64], f2s[64], ims[64];
    const int tid = threadIdx.x;
    if (tid < 64) {
        m2s[tid] = m2[b * NR + r0 + tid];
        f2s[tid] = f2[b * NR + r0 + tid];
        ims[tid] = (float)imask[b * NR + r0 + tid];
    }
    __syncthreads();
    {
        const int srow = tid >> 2, rg = (tid & 3) * 16;
        const int s = s0 + srow;
        const float m1v = m1[b * NS + s], f1v = f1[b * NS + s];
        const float smv = (float)smask[b * NS + s];
        const float* arow = att + ((size_t)b * NS + s) * NR + r0;
        const int w1swz = (s & 7) << 3;
        unsigned short* w1row = w1g + ((size_t)b * NS + s) * NR + r0;
        #pragma unroll
        for (int g = 0; g < 4; ++g) {
            const int rr = rg + g * 4;
            const float4 a = *reinterpret_cast<const float4*>(arow + rr);
            // w1 = exp(a - m1[s]) * f1[s] * im[r]
            const float e0 = expf(a.x - m1v) * f1v * ims[rr + 0];
            const float e1 = expf(a.y - m1v) * f1v * ims[rr + 1];
            const float e2 = expf(a.z - m1v) * f1v * ims[rr + 2];
            const float e3 = expf(a.w - m1v) * f1v * ims[rr + 3];
            uint2 u; u.x = pk2(e0, e1); u.y = pk2(e2, e3);
            *reinterpret_cast<uint2*>(w1row + (rr ^ w1swz)) = u;
            // w2 = exp(a - m2[r]) * f2[r] * sm[s]  -> transposed via LDS
            const float q0 = expf(a.x - m2s[rr + 0]) * f2s[rr + 0] * smv;
            const float q1 = expf(a.y - m2s[rr + 1]) * f2s[rr + 1] * smv;
            const float q2 = expf(a.z - m2s[rr + 2]) * f2s[rr + 2] * smv;
            const float q3 = expf(a.w - m2s[rr + 3]) * f2s[rr + 3] * smv;
            const unsigned t0 = pk2(q0, q1), t1 = pk2(q2, q3);
            T[rr + 0][srow] = (unsigned short)(t0 & 0xFFFF);
            T[rr + 1][srow] = (unsigned short)(t0 >> 16);
            T[rr + 2][srow] = (unsigned short)(t1 & 0xFFFF);
            T[rr + 3][srow] = (unsigned short)(t1 >> 16);
        }
    }
    __syncthreads();
    {
        const int rl = tid >> 2, sg = (tid & 3) * 16;
        const int w2swz = (rl & 7) << 3;
        unsigned short* w2row = w2g + ((size_t)b * NR + r0 + rl) * NS + s0;
        #pragma unroll
        for (int g = 0; g < 4; ++g) {
            const int ss = sg + g * 4;
            *reinterpret_cast<ushort4*>(w2row + (ss ^ w2swz)) =
                *reinterpret_cast<const ushort4*>(&T[rl][ss]);
        }
    }
}

// ================================================================ apply GEMM: C[64 m x 256 d] = A[m][K] @ Bt[d][K] (both pre-swizzled bf16)
template<int KTOT, int MT, bool WOUT, int WIDX>
__global__ __launch_bounds__(256) void gemm_apply(
    const unsigned short* __restrict__ Ag, const unsigned short* __restrict__ Btg,
    const float* __restrict__ ref, float* __restrict__ outp, double* __restrict__ wsum) {
    const int b = blockIdx.z, m0 = blockIdx.y * 64, d0 = blockIdx.x * 256;
    __shared__ unsigned short As[64 * 64];
    __shared__ unsigned short Bs[256 * 64];
    __shared__ float redsum[256];
    const int tid = threadIdx.x, lane = tid & 63, w = tid >> 6;
    const int fr = lane & 15, fq = lane >> 4;
    f32x4 acc[4][4];
    #pragma unroll
    for (int i = 0; i < 4; ++i)
        #pragma unroll
        for (int j = 0; j < 4; ++j) acc[i][j] = (f32x4){0.f, 0.f, 0.f, 0.f};

    const int srow = tid >> 3;             // 0..31 staging row
    const int scol = (tid & 7) * 16;       // byte offset in 128B chunk
    for (int kc = 0; kc < KTOT / 64; ++kc) {
        const char* asrc = (const char*)(Ag + ((size_t)b * MT + m0) * KTOT) + kc * 128 + scol;
        #pragma unroll
        for (int c = 0; c < 2; ++c)
            gload16(asrc + (size_t)(c * 32 + srow) * (KTOT * 2), (char*)As + (c * 256 + tid) * 16);
        const char* bsrc = (const char*)(Btg + ((size_t)b * DD + d0) * KTOT) + kc * 128 + scol;
        #pragma unroll
        for (int c = 0; c < 8; ++c)
            gload16(bsrc + (size_t)(c * 32 + srow) * (KTOT * 2), (char*)Bs + (c * 256 + tid) * 16);
        __syncthreads();
        #pragma unroll
        for (int ks = 0; ks < 2; ++ks) {
            bf16x8 aF[4], bF[4];
            #pragma unroll
            for (int mf = 0; mf < 4; ++mf) {
                const int row = mf * 16 + fr;
                const int pos = (ks * 32 + fq * 8) ^ ((row & 7) << 3);
                aF[mf] = *reinterpret_cast<const bf16x8*>(&As[row * 64 + pos]);
            }
            #pragma unroll
            for (int nf = 0; nf < 4; ++nf) {
                const int row = w * 64 + nf * 16 + fr;
                const int pos = (ks * 32 + fq * 8) ^ ((row & 7) << 3);
                bF[nf] = *reinterpret_cast<const bf16x8*>(&Bs[row * 64 + pos]);
            }
            #pragma unroll
            for (int mf = 0; mf < 4; ++mf)
                #pragma unroll
                for (int nf = 0; nf < 4; ++nf)
                    acc[mf][nf] = __builtin_amdgcn_mfma_f32_16x16x32_bf16(aF[mf], bF[nf], acc[mf][nf], 0, 0, 0);
        }
        __syncthreads();
    }
    float sumsq = 0.0f;
    #pragma unroll
    for (int mf = 0; mf < 4; ++mf) {
        #pragma unroll
        for (int i = 0; i < 4; ++i) {
            const int row = m0 + mf * 16 + fq * 4 + i;
            const size_t base = ((size_t)b * MT + row) * DD + d0 + w * 64;
            #pragma unroll
            for (int nf = 0; nf < 4; ++nf) {
                const float v = acc[mf][nf][i];
                const float rv = ref[base + nf * 16 + fr];
                if constexpr (WOUT) outp[base + nf * 16 + fr] = v;
                const float dx = rv - v;
                sumsq += dx * dx;
            }
        }
    }
    redsum[tid] = sumsq; __syncthreads();
    for (int off = 128; off; off >>= 1) {
        if (tid < off) redsum[tid] += redsum[tid + off];
        __syncthreads();
    }
    if (tid == 0) atomicAdd(wsum + WIDX, (double)redsum[0]);
}

// ================================================================ fallback f32 kernels (used when ws too small)
__global__ __launch_bounds__(256) void first_kernel(
    const float* __restrict__ span, const float* __restrict__ image,
    const int* __restrict__ smask, const int* __restrict__ imask,
    const float* __restrict__ att, float* __restrict__ att_first,
    double* __restrict__ ws) {
    const int b  = blockIdx.y;
    const int s0 = blockIdx.x * 32;
    __shared__ float wT[256][36];
    __shared__ float Is[32][132];
    __shared__ float red[256];
    const int tid  = threadIdx.x;
    const int lane = tid & 63, wave = tid >> 6;
    for (int i = 0; i < 8; ++i) {
        const int srel = wave * 8 + i;
        const int s    = s0 + srel;
        const float4 v = *reinterpret_cast<const float4*>(att + ((size_t)b * NS + s) * NR + lane * 4);
        float m = fmaxf(fmaxf(v.x, v.y), fmaxf(v.z, v.w));
        #pragma unroll
        for (int off = 32; off; off >>= 1) m = fmaxf(m, __shfl_xor(m, off));
        float4 e;
        e.x = expf(v.x - m); e.y = expf(v.y - m); e.z = expf(v.z - m); e.w = expf(v.w - m);
        float sum = e.x + e.y + e.z + e.w;
        #pragma unroll
        for (int off = 32; off; off >>= 1) sum += __shfl_xor(sum, off);
        const float fac = (float)smask[b * NS + s] / sum;
        const int4 im4 = *reinterpret_cast<const int4*>(imask + b * NR + lane * 4);
        wT[lane * 4 + 0][srel] = e.x * fac * (float)im4.x;
        wT[lane * 4 + 1][srel] = e.y * fac * (float)im4.y;
        wT[lane * 4 + 2][srel] = e.z * fac * (float)im4.z;
        wT[lane * 4 + 3][srel] = e.w * fac * (float)im4.w;
    }
    __syncthreads();
    float sumsq = 0.0f;
    const int txd = tid & 31;
    const int tys = tid >> 5;
    const float* Ib = image + (size_t)b * NR * DD;
    for (int dc = 0; dc < 8; ++dc) {
        const int d0 = dc * 128;
        float acc[4][4] = {};
        for (int rc = 0; rc < 8; ++rc) {
            const int r0 = rc * 32;
            {
                const int rr = tid >> 3;
                const int cb = tid & 7;
                const float* src = Ib + (size_t)(r0 + rr) * DD + d0;
                #pragma unroll
                for (int q = 0; q < 4; ++q)
                    *reinterpret_cast<float4*>(&Is[rr][(cb + 8 * q) * 4]) =
                        *reinterpret_cast<const float4*>(src + (cb + 8 * q) * 4);
            }
            __syncthreads();
            #pragma unroll 4
            for (int rr = 0; rr < 32; ++rr) {
                const float4 wv = *reinterpret_cast<const float4*>(&wT[r0 + rr][tys * 4]);
                const float4 iv = *reinterpret_cast<const float4*>(&Is[rr][txd * 4]);
                const float wvv[4] = {wv.x, wv.y, wv.z, wv.w};
                const float ivv[4] = {iv.x, iv.y, iv.z, iv.w};
                #pragma unroll
                for (int i = 0; i < 4; ++i)
                    #pragma unroll
                    for (int j = 0; j < 4; ++j)
                        acc[i][j] += wvv[i] * ivv[j];
            }
            __syncthreads();
        }
        #pragma unroll
        for (int i = 0; i < 4; ++i) {
            const int s = s0 + tys * 4 + i;
            const size_t base = ((size_t)b * NS + s) * DD + d0 + txd * 4;
            const float4 af = {acc[i][0], acc[i][1], acc[i][2], acc[i][3]};
            *reinterpret_cast<float4*>(att_first + base) = af;
            const float4 sp = *reinterpret_cast<const float4*>(span + base);
            float dx;
            dx = sp.x - af.x; sumsq += dx * dx;
            dx = sp.y - af.y; sumsq += dx * dx;
            dx = sp.z - af.z; sumsq += dx * dx;
            dx = sp.w - af.w; sumsq += dx * dx;
        }
    }
    red[tid] = sumsq; __syncthreads();
    for (int off = 128; off; off >>= 1) {
        if (tid < off) red[tid] += red[tid + off];
        __syncthreads();
    }
    if (tid == 0) atomicAdd(ws, (double)red[0]);
}

__global__ __launch_bounds__(256) void second_kernel(
    const float* __restrict__ span, const float* __restrict__ image,
    const int* __restrict__ smask, const int* __restrict__ imask,
    const float* __restrict__ att, double* __restrict__ ws) {
    const int b  = blockIdx.y;
    const int r0 = blockIdx.x * 32;
    __shared__ float w2s[32][36];
    __shared__ float Ss[32][132];
    __shared__ float mArr[32], fArr[32];
    __shared__ float redm[8][32];
    __shared__ float red[256];
    const int tid = threadIdx.x;
    const int rr = tid & 31, q = tid >> 5;
    const float* attb = att + (size_t)b * NS * NR + r0 + rr;
    float mloc = -3.4e38f;
    for (int t = 0; t < 64; ++t)
        mloc = fmaxf(mloc, attb[(size_t)(q * 64 + t) * NR]);
    redm[q][rr] = mloc;
    __syncthreads();
    if (tid < 32) {
        float m = redm[0][tid];
        #pragma unroll
        for (int qq = 1; qq < 8; ++qq) m = fmaxf(m, redm[qq][tid]);
        mArr[tid] = m;
    }
    __syncthreads();
    const float mcol = mArr[rr];
    float sloc = 0.0f;
    for (int t = 0; t < 64; ++t)
        sloc += expf(attb[(size_t)(q * 64 + t) * NR] - mcol);
    redm[q][rr] = sloc;
    __syncthreads();
    if (tid < 32) {
        float s = 0.0f;
        #pragma unroll
        for (int qq = 0; qq < 8; ++qq) s += redm[qq][tid];
        fArr[tid] = (float)imask[b * NR + r0 + tid] / s;
    }
    __syncthreads();
    float sumsq = 0.0f;
    const int txd = tid & 31;
    const int tyr = tid >> 5;
    const float* Sb = span + (size_t)b * NS * DD;
    for (int dc = 0; dc < 8; ++dc) {
        const int d0 = dc * 128;
        float acc[4][4] = {};
        for (int sc = 0; sc < 16; ++sc) {
            const int sb0 = sc * 32;
            {
                const int sr = tid >> 3;
                const int cb = tid & 7;
                const float* src = Sb + (size_t)(sb0 + sr) * DD + d0;
                #pragma unroll
                for (int qq = 0; qq < 4; ++qq)
                    *reinterpret_cast<float4*>(&Ss[sr][(cb + 8 * qq) * 4]) =
                        *reinterpret_cast<const float4*>(src + (cb + 8 * qq) * 4);
            }
            {
                const int ss = tid >> 3;
                const int rq = (tid & 7) * 4;
                const int s  = sb0 + ss;
                const float4 v = *reinterpret_cast<const float4*>(att + ((size_t)b * NS + s) * NR + r0 + rq);
                const float smv = (float)smask[b * NS + s];
                float4 wv;
                wv.x = expf(v.x - mArr[rq + 0]) * fArr[rq + 0] * smv;
                wv.y = expf(v.y - mArr[rq + 1]) * fArr[rq + 1] * smv;
                wv.z = expf(v.z - mArr[rq + 2]) * fArr[rq + 2] * smv;
                wv.w = expf(v.w - mArr[rq + 3]) * fArr[rq + 3] * smv;
                *reinterpret_cast<float4*>(&w2s[ss][rq]) = wv;
            }
            __syncthreads();
            #pragma unroll 4
            for (int ss = 0; ss < 32; ++ss) {
                const float4 wv = *reinterpret_cast<const float4*>(&w2s[ss][tyr * 4]);
                const float4 sv = *reinterpret_cast<const float4*>(&Ss[ss][txd * 4]);
                const float wvv[4] = {wv.x, wv.y, wv.z, wv.w};
                const float svv[4] = {sv.x, sv.y, sv.z, sv.w};
                #pragma unroll
                for (int i = 0; i < 4; ++i)
                    #pragma unroll
                    for (int j = 0; j < 4; ++j)
                        acc[i][j] += wvv[i] * svv[j];
            }
            __syncthreads();
        }
        #pragma unroll
        for (int i = 0; i < 4; ++i) {
            const int r = r0 + tyr * 4 + i;
            const float4 iv = *reinterpret_cast<const float4*>(image + ((size_t)b * NR + r) * DD + d0 + txd * 4);
            float dx;
            dx = iv.x - acc[i][0]; sumsq += dx * dx;
            dx = iv.y - acc[i][1]; sumsq += dx * dx;
            dx = iv.z - acc[i][2]; sumsq += dx * dx;
            dx = iv.w - acc[i][3]; sumsq += dx * dx;
        }
    }
    red[tid] = sumsq; __syncthreads();
    for (int off = 128; off; off >>= 1) {
        if (tid < off) red[tid] += red[tid + off];
        __syncthreads();
    }
    if (tid == 0) atomicAdd(ws + 1, (double)red[0]);
}

// ---------------------------------------------------------------- final score
__global__ __launch_bounds__(64) void score_kernel(const double* __restrict__ ws, float* __restrict__ out) {
    if (threadIdx.x == 0) {
        out[0] = (float)(ws[0] / (double)((size_t)B_ * NS * DD) +
                         ws[1] / (double)((size_t)B_ * NR * DD));
    }
}

extern "C" void kernel_launch(void* const* d_in, const int* in_sizes, int n_in,
                              void* d_out, int out_size, void* d_ws, size_t ws_size,
                              hipStream_t stream) {
    const float* span  = (const float*)d_in[0];
    const float* image = (const float*)d_in[1];
    const int*   smask = (const int*)d_in[2];
    const int*   imask = (const int*)d_in[3];
    float* out       = (float*)d_out;
    float* att_first = out + 1;
    float* att       = out + 1 + (size_t)B_ * NS * DD;

    // ws layout:
    //  wsum(512B) | m1,f1 (B*NS f32 each) | m2,f2 (B*NR f32 each)
    //  | rowP (B*NS*2 float2) | colP (B*NR*4 float2)
    //  | X0: imgT [0,32M) , w1 [32M,48M)  -> phase 1
    //        spT  [0,64M)                 -> phase 2 (overwrites imgT,w1)
    //        w2   [64M,80M)               -> live across both
    char* base = (char*)d_ws;
    double* wsum = (double*)base;
    float* m1 = (float*)(base + 512);
    float* f1 = m1 + (size_t)B_ * NS;
    float* m2 = f1 + (size_t)B_ * NS;
    float* f2 = m2 + (size_t)B_ * NR;
    float2* rowP = (float2*)(f2 + (size_t)B_ * NR);
    float2* colP = rowP + (size_t)B_ * NS * 2;
    char* X0 = (char*)(colP + (size_t)B_ * NR * 4);
    unsigned short* imgT = (unsigned short*)X0;
    unsigned short* w1g  = (unsigned short*)(X0 + (size_t)B_ * DD * NR * 2);
    unsigned short* spT  = (unsigned short*)X0;
    unsigned short* w2g  = (unsigned short*)(X0 + (size_t)B_ * DD * NS * 2);
    const size_t NEED = (size_t)(X0 - base) + (size_t)B_ * DD * NS * 2 + (size_t)B_ * NS * NR * 2;
    const int wsok = (ws_size >= NEED) ? 1 : 0;

    zero_ws<<<dim3(1), dim3(64), 0, stream>>>(wsum);
    att_mfma<<<dim3(NR / 128, NS / 128, B_), dim3(256), 0, stream>>>(
        span, image, smask, imask, att, rowP, colP, wsok);

    if (wsok) {
        combine_stats<<<dim3((B_ * NS + B_ * NR) / 256), dim3(256), 0, stream>>>(
            rowP, colP, smask, imask, m1, f1, m2, f2);
        transpose_swz<<<dim3(DD / 32, NR / 32, B_), dim3(256), 0, stream>>>(image, imgT, NR);
        build_w12<<<dim3(NR / 64, NS / 64, B_), dim3(256), 0, stream>>>(
            att, smask, imask, m1, f1, m2, f2, w1g, w2g);
        gemm_apply<NR, NS, true, 0><<<dim3(DD / 256, NS / 64, B_), dim3(256), 0, stream>>>(
            w1g, imgT, span, att_first, wsum);
        transpose_swz<<<dim3(DD / 32, NS / 32, B_), dim3(256), 0, stream>>>(span, spT, NS);
        gemm_apply<NS, NR, false, 1><<<dim3(DD / 256, NR / 64, B_), dim3(256), 0, stream>>>(
            w2g, spT, image, nullptr, wsum);
    } else {
        first_kernel<<<dim3(NS / 32, B_), dim3(256), 0, stream>>>(span, image, smask, imask, att, att_first, wsum);
        second_kernel<<<dim3(NR / 32, B_), dim3(256), 0, stream>>>(span, image, smask, imask, att, wsum);
    }
    score_kernel<<<dim3(1), dim3(64), 0, stream>>>(wsum, out);
}